// Round 4
// baseline (437.732 us; speedup 1.0000x reference)
//
#include <hip/hip_runtime.h>

#define DD 1280
#define SS 2048
#define HH 20

typedef __bf16 bf16x8 __attribute__((ext_vector_type(8)));
typedef float f32x4 __attribute__((ext_vector_type(4)));

typedef __attribute__((address_space(3))) unsigned int lds_uint;
typedef __attribute__((address_space(1))) unsigned int glb_uint;
#define GLL16(g, l) __builtin_amdgcn_global_load_lds((const glb_uint*)(g), (lds_uint*)(l), 16, 0, 0)

__device__ __forceinline__ unsigned short f2bf(float f) {
  union { float f; unsigned u; } v; v.f = f;
  unsigned r = v.u + 0x7fffu + ((v.u >> 16) & 1u);
  return (unsigned short)(r >> 16);
}
__device__ __forceinline__ unsigned f2u(float f) {
  union { float f; unsigned u; } v; v.f = f; return v.u;
}

// ---- prep: cast X to bf16; transpose-cast W -> WT[n][k]; rotary cos/sin table ----
__global__ __launch_bounds__(256) void prep_kernel(
    const float* __restrict__ X, const float* __restrict__ Wq,
    const float* __restrict__ Wk, const float* __restrict__ Wv,
    unsigned short* __restrict__ Xb, unsigned short* __restrict__ WT,
    float2* __restrict__ cs) {
  __shared__ unsigned short tile[32][33];
  int bid = blockIdx.x, tid = threadIdx.x;
  if (bid < 2560) {
    size_t base = (size_t)bid * 2048 + (size_t)tid * 8;
    const float4* xin = (const float4*)(X + base);
    float4 a = xin[0], c = xin[1];
    ushort4 o0 = make_ushort4(f2bf(a.x), f2bf(a.y), f2bf(a.z), f2bf(a.w));
    ushort4 o1 = make_ushort4(f2bf(c.x), f2bf(c.y), f2bf(c.z), f2bf(c.w));
    *(ushort4*)(Xb + base) = o0;
    *(ushort4*)(Xb + base + 4) = o1;
  } else if (bid < 7360) {
    int wb = bid - 2560;          // 3 * 1600 tiles of 32x32
    int mat = wb / 1600;
    int t = wb % 1600;
    int tn = t % 40, tk = t / 40;
    const float* W = (mat == 0) ? Wq : ((mat == 1) ? Wk : Wv);
    int k0 = tk * 32, n0 = tn * 32;
    int tc = tid & 31, tr = tid >> 5;
#pragma unroll
    for (int i = 0; i < 4; i++) {
      int kl = tr + i * 8;
      tile[kl][tc] = f2bf(W[(size_t)(k0 + kl) * DD + n0 + tc]);
    }
    __syncthreads();
    unsigned short* out = WT + (size_t)mat * DD * DD;
#pragma unroll
    for (int i = 0; i < 4; i++) {
      int nl = tr + i * 8;
      out[(size_t)(n0 + nl) * DD + k0 + tc] = tile[tc][nl];
    }
  } else {
    // rotary table: cs[sp][j] = (cos, sin)(sp * 10000^(-j/32)), 2048 x 32
    int idx = (bid - 7360) * 256 + tid;     // 256 blocks -> 65536 entries
    int sp = idx >> 5, j = idx & 31;
    float invf = exp2f(-(float)j * 0.41524101186092034f);
    float ang = (float)sp * invf;
    cs[idx] = make_float2(cosf(ang), sinf(ang));
  }
}

// ---- QKV GEMM (m97 structure) + fused bias + rotary (table) epilogue ----
// Q additionally scaled by HD^-0.5 * log2(e) so attention can use exp2 directly.
__global__ __launch_bounds__(256) void qkv_gemm_kernel(
    const unsigned short* __restrict__ Xb, const unsigned short* __restrict__ WT,
    const float* __restrict__ bq, const float* __restrict__ bk, const float* __restrict__ bv,
    const float2* __restrict__ cs,
    unsigned short* __restrict__ Qr, unsigned short* __restrict__ Kr,
    unsigned short* __restrict__ VT) {
  __shared__ __align__(16) unsigned short As[128 * 32];
  __shared__ __align__(16) unsigned short Bs[128 * 32];
  int bx = blockIdx.x;            // 3 * 32 * 10
  int mat = bx / 320;
  int r0 = bx % 320;
  int tm = r0 / 10, tn = r0 % 10;
  int m0 = tm * 128, n0 = tn * 128;
  int tid = threadIdx.x;
  int lane = tid & 63, wave = tid >> 6;
  int c15 = lane & 15, quad = lane >> 4;
  int wm = wave >> 1, wn = wave & 1;
  const unsigned short* Wm = WT + (size_t)mat * DD * DD;

  int rowA = tid >> 2;
  int c8 = (tid & 3) * 8;
  const unsigned short* gA0 = Xb + (size_t)(m0 + rowA) * DD + c8;
  const unsigned short* gA1 = gA0 + (size_t)64 * DD;
  const unsigned short* gB0 = Wm + (size_t)(n0 + rowA) * DD + c8;
  const unsigned short* gB1 = gB0 + (size_t)64 * DD;
  unsigned short* ldsA0 = As + wave * 512;          // rows 0..63
  unsigned short* ldsA1 = As + 2048 + wave * 512;   // rows 64..127
  unsigned short* ldsB0 = Bs + wave * 512;
  unsigned short* ldsB1 = Bs + 2048 + wave * 512;

  f32x4 acc[4][4] = {};

  for (int kk = 0; kk < DD; kk += 32) {
    __syncthreads();
    GLL16(gA0 + kk, ldsA0);
    GLL16(gA1 + kk, ldsA1);
    GLL16(gB0 + kk, ldsB0);
    GLL16(gB1 + kk, ldsB1);
    __syncthreads();
    bf16x8 af[4];
#pragma unroll
    for (int mi = 0; mi < 4; mi++)
      af[mi] = *(const bf16x8*)(As + (wm * 64 + mi * 16 + c15) * 32 + quad * 8);
#pragma unroll
    for (int ni = 0; ni < 4; ni++) {
      bf16x8 bfr = *(const bf16x8*)(Bs + (wn * 64 + ni * 16 + c15) * 32 + quad * 8);
#pragma unroll
      for (int mi = 0; mi < 4; mi++)
        acc[mi][ni] = __builtin_amdgcn_mfma_f32_16x16x32_bf16(af[mi], bfr, acc[mi][ni], 0, 0, 0);
    }
  }

  int growb = m0 + wm * 64;
  int gcolb = n0 + wn * 64;
  if (mat == 2) {
    // V: write transposed VT[(b*H+h)*64+d][s]
#pragma unroll
    for (int mi = 0; mi < 4; mi++) {
      int row0 = growb + mi * 16 + quad * 4;
      int bb_ = row0 >> 11, sp = row0 & 2047;
#pragma unroll
      for (int ni = 0; ni < 4; ni++) {
        int gcol = gcolb + ni * 16 + c15;
        float bias = bv[gcol];
        int hh = gcol >> 6, dd = gcol & 63;
        f32x4 v = acc[mi][ni];
        ushort4 o = make_ushort4(f2bf(v[0] + bias), f2bf(v[1] + bias),
                                 f2bf(v[2] + bias), f2bf(v[3] + bias));
        *(ushort4*)(VT + ((size_t)((bb_ * HH + hh) * 64 + dd)) * SS + sp) = o;
      }
    }
  } else {
    // Q / K: bias + rotary via cs table; each wave's 64 cols = exactly one head,
    // rotary pair (d, d+32) = acc frags (ni, ni+2), same lane.
    unsigned short* Out = (mat == 0) ? Qr : Kr;
    const float* bias = (mat == 0) ? bq : bk;
    float qs = (mat == 0) ? 0.18033688011112042f : 1.0f;  // 0.125*log2(e) for Q
#pragma unroll
    for (int mi = 0; mi < 4; mi++) {
      int row0 = growb + mi * 16 + quad * 4;
#pragma unroll
      for (int ni = 0; ni < 2; ni++) {
        int gcol_lo = gcolb + ni * 16 + c15;      // d in [0,32) within head
        int gcol_hi = gcol_lo + 32;
        float blo = bias[gcol_lo], bhi = bias[gcol_hi];
        int d = ni * 16 + c15;
        f32x4 lo = acc[mi][ni], hi = acc[mi][ni + 2];
#pragma unroll
        for (int r = 0; r < 4; r++) {
          int grow = row0 + r;
          float2 cv = cs[(size_t)(grow & 2047) * 32 + d];
          float xl = (lo[r] + blo) * qs, xh = (hi[r] + bhi) * qs;
          Out[(size_t)grow * DD + gcol_lo] = f2bf(xl * cv.x - xh * cv.y);
          Out[(size_t)grow * DD + gcol_hi] = f2bf(xh * cv.x + xl * cv.y);
        }
      }
    }
  }
}

// ---- flash attention v10: v6 structure (known-good P-strip path, byte-identical)
// + Q moved from 32 resident VGPRs to an 8 KB LDS buffer read on demand.
// Rationale (rocprof v6): MfmaUtil 19.8 / VALUBusy 17.8 / HBM 3% / Occupancy
// 19.5% -> latency-bound at 2 waves/SIMD (112 arch + 80 acc ~= 192 regs).
// Q is block-uniform (waves split keys, not queries), so the per-wave qf copy
// is pure register waste.  Staged once via global_load_lds in fragment order
// (slot (mi,kc,lane) at lane*16B -> conflict-free ds_read_b128), then the QK
// loop loads qv on demand with kc-outer order (per-accumulator kc sequence
// unchanged -> bitwise-identical results).  ~168 total regs -> 3 waves/SIMD;
// LDS 40.5 KB -> 3 blocks/CU (matches).  Spill tripwire: attn WRITE_SIZE > 0.
__device__ __forceinline__ void attn_load_frags(
    bf16x8 (&kf)[2][2], bf16x8 (&vf)[4],
    const unsigned short* Kt, const unsigned short* Vt, int c15, int quad) {
#pragma unroll
  for (int ni = 0; ni < 2; ni++)
#pragma unroll
    for (int kc = 0; kc < 2; kc++)
      kf[ni][kc] = *(const bf16x8*)(Kt + (size_t)(ni * 16 + c15) * DD + kc * 32 + quad * 8);
#pragma unroll
  for (int nio = 0; nio < 4; nio++)
    vf[nio] = *(const bf16x8*)(Vt + (size_t)(nio * 16 + c15) * SS + quad * 8);
}

__device__ __forceinline__ void attn_tile(
    const unsigned short* Qs, int lane,
    const bf16x8 (&kf)[2][2], const bf16x8 (&vf)[4],
    const bf16x8& ones, f32x4 (&of)[4][4], f32x4 (&ol)[4],
    unsigned short* Pw, int c15, int quad) {
  // S = Q K^T  (64q x 32k per wave); qv loaded on demand from Qlds
  f32x4 sc[4][2] = {};
#pragma unroll
  for (int kc = 0; kc < 2; kc++)
#pragma unroll
    for (int mi = 0; mi < 4; mi++) {
      bf16x8 qv = *(const bf16x8*)(Qs + ((mi * 2 + kc) * 64 + lane) * 8);
#pragma unroll
      for (int ni = 0; ni < 2; ni++)
        sc[mi][ni] = __builtin_amdgcn_mfma_f32_16x16x32_bf16(qv, kf[ni][kc], sc[mi][ni], 0, 0, 0);
    }

  int pos_r = (quad + 2 * ((c15 >> 2) & 3) + (c15 & 3)) & 7;   // read-side swizzle

#define PROD(mi)                                                              \
  {                                                                           \
    _Pragma("unroll")                                                         \
    for (int ni = 0; ni < 2; ni++) {                                          \
      int kc8 = ni * 2 + (c15 >> 3);                                          \
      _Pragma("unroll")                                                       \
      for (int r = 0; r < 4; r++) {                                           \
        unsigned u = f2u(__builtin_amdgcn_exp2f(sc[mi][ni][r]));              \
        int q = (mi) * 16 + quad * 4 + r;                                     \
        int pos = (kc8 + 2 * quad + r) & 7;                                   \
        Pw[q * 64 + pos * 8 + (c15 & 7)] = (unsigned short)(u >> 16);         \
      }                                                                       \
    }                                                                         \
  }
#define CONS(mi)                                                              \
  {                                                                           \
    bf16x8 pf = *(const bf16x8*)(Pw + ((mi) * 16 + c15) * 64 + pos_r * 8);    \
    _Pragma("unroll")                                                         \
    for (int nio = 0; nio < 4; nio++)                                         \
      of[mi][nio] = __builtin_amdgcn_mfma_f32_16x16x32_bf16(pf, vf[nio],      \
                                                            of[mi][nio], 0, 0, 0); \
    ol[mi] = __builtin_amdgcn_mfma_f32_16x16x32_bf16(pf, ones, ol[mi], 0, 0, 0); \
  }

  PROD(0);
  PROD(1); CONS(0);
  PROD(2); CONS(1);
  PROD(3); CONS(2);
  CONS(3);
#undef PROD
#undef CONS
}

__global__ __launch_bounds__(256)
__attribute__((amdgpu_waves_per_eu(3, 4)))
void attn_kernel(
    const unsigned short* __restrict__ Qr, const unsigned short* __restrict__ Kr,
    const unsigned short* __restrict__ VT, float* __restrict__ out) {
  __shared__ __align__(16) unsigned short Pall[4 * 64 * 64];  // 32 KB: per-wave P strips
  __shared__ __align__(16) unsigned short Qlds[512 * 8];      // 8 KB: Q frags (mi,kc,lane)
  __shared__ float Lbuf[64];
  int bx = blockIdx.x;             // bx = qt*40 + bh; head pinned to one XCD (40%8==0)
  int bh = bx % 40, qt = bx / 40;
  int b = bh / HH, h = bh % HH;
  int tid = threadIdx.x;
  int lane = tid & 63, w = tid >> 6;
  int c15 = lane & 15, quad = lane >> 4;
  int q0 = qt * 64;

  // stage Q fragments (block-uniform) into LDS via global_load_lds.
  // wave w stages (mi = w>>1, kc = w&1) and (mi = 2+(w>>1), kc = w&1);
  // lane l's 16B lands at slot ((mi*2+kc)*64 + l)*8 shorts.
  {
    int mis = w >> 1, kcs = w & 1;
    const unsigned short* s0 = Qr + (size_t)(b * SS + q0 + mis * 16 + c15) * DD
                               + h * 64 + kcs * 32 + quad * 8;
    GLL16(s0, Qlds + (size_t)(w * 64) * 8);
    GLL16(s0 + (size_t)32 * DD, Qlds + (size_t)((4 + w) * 64) * 8);
  }

  const unsigned short* Kbase = Kr + (size_t)(b * SS + w * 32) * DD + h * 64;
  const unsigned short* Vbase = VT + (size_t)(bh * 64) * SS + w * 32;
  unsigned short* Pw = Pall + w * 4096;   // 64 rows x 64 shorts

  bf16x8 ones;
#pragma unroll
  for (int i = 0; i < 8; i++) ones[i] = (__bf16)1.0f;

  f32x4 of[4][4] = {};       // [mi][nio]
  f32x4 ol[4] = {};          // l via P*ones

  bf16x8 kfb[2][2][2], vfb[2][4];   // double-buffered K/V fragments
  attn_load_frags(kfb[0], vfb[0], Kbase, Vbase, c15, quad);

  __syncthreads();           // Qlds ready (drains global_load_lds)

  for (int t = 0; t < 16; t += 2) {
    // issue t+1 loads into buf1 before computing buf0
    attn_load_frags(kfb[1], vfb[1],
                    Kbase + (size_t)((t + 1) * 128) * DD, Vbase + (t + 1) * 128,
                    c15, quad);
    attn_tile(Qlds, lane, kfb[0], vfb[0], ones, of, ol, Pw, c15, quad);
    if (t + 2 < 16)
      attn_load_frags(kfb[0], vfb[0],
                      Kbase + (size_t)((t + 2) * 128) * DD, Vbase + (t + 2) * 128,
                      c15, quad);
    attn_tile(Qlds, lane, kfb[1], vfb[1], ones, of, ol, Pw, c15, quad);
  }

  // all waves done with their P strips -> safe to overlay Obuf on Pall
  __syncthreads();
  float* Obuf = (float*)Pall;      // 64 x 65 floats = 16.6 KB of the 32 KB strip area

  // cross-wave reduction of O and l (serialized passes)
  for (int pass = 0; pass < 4; pass++) {
    if (w == pass) {
#pragma unroll
      for (int mi = 0; mi < 4; mi++)
#pragma unroll
        for (int nio = 0; nio < 4; nio++)
#pragma unroll
          for (int r = 0; r < 4; r++) {
            int q = mi * 16 + quad * 4 + r;
            int d = nio * 16 + c15;
            if (pass == 0) Obuf[q * 65 + d] = of[mi][nio][r];
            else           Obuf[q * 65 + d] += of[mi][nio][r];
          }
      if (c15 == 0) {
#pragma unroll
        for (int mi = 0; mi < 4; mi++)
#pragma unroll
          for (int r = 0; r < 4; r++) {
            int q = mi * 16 + quad * 4 + r;
            if (pass == 0) Lbuf[q] = ol[mi][r];
            else           Lbuf[q] += ol[mi][r];
          }
      }
    }
    __syncthreads();
  }

  // epilogue: each wave writes 16 q-rows; lane covers 16 consecutive d
  {
    int row = w * 16 + (lane >> 2);
    int col0 = (lane & 3) * 16;
    float invl = 1.0f / Lbuf[row];
    float* op = out + (size_t)(b * SS + q0 + row) * DD + h * 64 + col0;
    const float* ob = Obuf + row * 65 + col0;
#pragma unroll
    for (int j = 0; j < 4; j++) {
      float4 v = make_float4(ob[j * 4 + 0] * invl, ob[j * 4 + 1] * invl,
                             ob[j * 4 + 2] * invl, ob[j * 4 + 3] * invl);
      *(float4*)(op + j * 4) = v;
    }
  }
}

extern "C" void kernel_launch(void* const* d_in, const int* in_sizes, int n_in,
                              void* d_out, int out_size, void* d_ws, size_t ws_size,
                              hipStream_t stream) {
  (void)in_sizes; (void)n_in; (void)out_size; (void)ws_size;
  const float* X  = (const float*)d_in[0];
  const float* Wq = (const float*)d_in[1];
  const float* bq = (const float*)d_in[2];
  const float* Wk = (const float*)d_in[3];
  const float* bk = (const float*)d_in[4];
  const float* Wv = (const float*)d_in[5];
  const float* bv = (const float*)d_in[6];
  char* ws = (char*)d_ws;
  unsigned short* Xb  = (unsigned short*)(ws);                 // 4096x1280 bf16
  unsigned short* WT  = (unsigned short*)(ws + 10485760);      // 3x1280x1280 bf16 (transposed)
  unsigned short* Qr  = (unsigned short*)(ws + 20316160);      // 4096x1280 bf16 (rotary'd, scaled)
  unsigned short* Kr  = (unsigned short*)(ws + 30801920);      // 4096x1280 bf16 (rotary'd)
  unsigned short* VTt = (unsigned short*)(ws + 41287680);      // [40][64][2048] bf16
  float2* cstab       = (float2*)(ws + 51773440);              // 2048x32 float2
  hipLaunchKernelGGL(prep_kernel, dim3(7616), dim3(256), 0, stream, X, Wq, Wk, Wv, Xb, WT, cstab);
  hipLaunchKernelGGL(qkv_gemm_kernel, dim3(960), dim3(256), 0, stream, Xb, WT, bq, bk, bv, cstab, Qr, Kr, VTt);
  hipLaunchKernelGGL(attn_kernel, dim3(1280), dim3(256), 0, stream, Qr, Kr, VTt, (float*)d_out);
}

// Round 5
// 300.270 us; speedup vs baseline: 1.4578x; 1.4578x over previous
//
#include <hip/hip_runtime.h>

#define DD 1280
#define SS 2048
#define HH 20

typedef __bf16 bf16x8 __attribute__((ext_vector_type(8)));
typedef float f32x4 __attribute__((ext_vector_type(4)));

typedef __attribute__((address_space(3))) unsigned int lds_uint;
typedef __attribute__((address_space(1))) unsigned int glb_uint;
#define GLL16(g, l) __builtin_amdgcn_global_load_lds((const glb_uint*)(g), (lds_uint*)(l), 16, 0, 0)

__device__ __forceinline__ unsigned short f2bf(float f) {
  union { float f; unsigned u; } v; v.f = f;
  unsigned r = v.u + 0x7fffu + ((v.u >> 16) & 1u);
  return (unsigned short)(r >> 16);
}
__device__ __forceinline__ unsigned f2u(float f) {
  union { float f; unsigned u; } v; v.f = f; return v.u;
}
__device__ __forceinline__ float u2f(unsigned x) {
  union { unsigned u; float f; } v; v.u = x; return v.f;
}

// ---- prep: cast X to bf16; transpose-cast W -> WT[n][k]; rotary cos/sin table ----
__global__ __launch_bounds__(256) void prep_kernel(
    const float* __restrict__ X, const float* __restrict__ Wq,
    const float* __restrict__ Wk, const float* __restrict__ Wv,
    unsigned short* __restrict__ Xb, unsigned short* __restrict__ WT,
    float2* __restrict__ cs) {
  __shared__ unsigned short tile[32][33];
  int bid = blockIdx.x, tid = threadIdx.x;
  if (bid < 2560) {
    size_t base = (size_t)bid * 2048 + (size_t)tid * 8;
    const float4* xin = (const float4*)(X + base);
    float4 a = xin[0], c = xin[1];
    ushort4 o0 = make_ushort4(f2bf(a.x), f2bf(a.y), f2bf(a.z), f2bf(a.w));
    ushort4 o1 = make_ushort4(f2bf(c.x), f2bf(c.y), f2bf(c.z), f2bf(c.w));
    *(ushort4*)(Xb + base) = o0;
    *(ushort4*)(Xb + base + 4) = o1;
  } else if (bid < 7360) {
    int wb = bid - 2560;          // 3 * 1600 tiles of 32x32
    int mat = wb / 1600;
    int t = wb % 1600;
    int tn = t % 40, tk = t / 40;
    const float* W = (mat == 0) ? Wq : ((mat == 1) ? Wk : Wv);
    int k0 = tk * 32, n0 = tn * 32;
    int tc = tid & 31, tr = tid >> 5;
#pragma unroll
    for (int i = 0; i < 4; i++) {
      int kl = tr + i * 8;
      tile[kl][tc] = f2bf(W[(size_t)(k0 + kl) * DD + n0 + tc]);
    }
    __syncthreads();
    unsigned short* out = WT + (size_t)mat * DD * DD;
#pragma unroll
    for (int i = 0; i < 4; i++) {
      int nl = tr + i * 8;
      out[(size_t)(n0 + nl) * DD + k0 + tc] = tile[tc][nl];
    }
  } else {
    // rotary table: cs[sp][j] = (cos, sin)(sp * 10000^(-j/32)), 2048 x 32
    int idx = (bid - 7360) * 256 + tid;     // 256 blocks -> 65536 entries
    int sp = idx >> 5, j = idx & 31;
    float invf = exp2f(-(float)j * 0.41524101186092034f);
    float ang = (float)sp * invf;
    cs[idx] = make_float2(cosf(ang), sinf(ang));
  }
}

// ---- QKV GEMM (m97 structure) + fused bias + rotary (table) epilogue ----
// Q additionally scaled by HD^-0.5 * log2(e) so attention can use exp2 directly.
__global__ __launch_bounds__(256) void qkv_gemm_kernel(
    const unsigned short* __restrict__ Xb, const unsigned short* __restrict__ WT,
    const float* __restrict__ bq, const float* __restrict__ bk, const float* __restrict__ bv,
    const float2* __restrict__ cs,
    unsigned short* __restrict__ Qr, unsigned short* __restrict__ Kr,
    unsigned short* __restrict__ VT) {
  __shared__ __align__(16) unsigned short As[128 * 32];
  __shared__ __align__(16) unsigned short Bs[128 * 32];
  int bx = blockIdx.x;            // 3 * 32 * 10
  int mat = bx / 320;
  int r0 = bx % 320;
  int tm = r0 / 10, tn = r0 % 10;
  int m0 = tm * 128, n0 = tn * 128;
  int tid = threadIdx.x;
  int lane = tid & 63, wave = tid >> 6;
  int c15 = lane & 15, quad = lane >> 4;
  int wm = wave >> 1, wn = wave & 1;
  const unsigned short* Wm = WT + (size_t)mat * DD * DD;

  int rowA = tid >> 2;
  int c8 = (tid & 3) * 8;
  const unsigned short* gA0 = Xb + (size_t)(m0 + rowA) * DD + c8;
  const unsigned short* gA1 = gA0 + (size_t)64 * DD;
  const unsigned short* gB0 = Wm + (size_t)(n0 + rowA) * DD + c8;
  const unsigned short* gB1 = gB0 + (size_t)64 * DD;
  unsigned short* ldsA0 = As + wave * 512;          // rows 0..63
  unsigned short* ldsA1 = As + 2048 + wave * 512;   // rows 64..127
  unsigned short* ldsB0 = Bs + wave * 512;
  unsigned short* ldsB1 = Bs + 2048 + wave * 512;

  f32x4 acc[4][4] = {};

  for (int kk = 0; kk < DD; kk += 32) {
    __syncthreads();
    GLL16(gA0 + kk, ldsA0);
    GLL16(gA1 + kk, ldsA1);
    GLL16(gB0 + kk, ldsB0);
    GLL16(gB1 + kk, ldsB1);
    __syncthreads();
    bf16x8 af[4];
#pragma unroll
    for (int mi = 0; mi < 4; mi++)
      af[mi] = *(const bf16x8*)(As + (wm * 64 + mi * 16 + c15) * 32 + quad * 8);
#pragma unroll
    for (int ni = 0; ni < 4; ni++) {
      bf16x8 bfr = *(const bf16x8*)(Bs + (wn * 64 + ni * 16 + c15) * 32 + quad * 8);
#pragma unroll
      for (int mi = 0; mi < 4; mi++)
        acc[mi][ni] = __builtin_amdgcn_mfma_f32_16x16x32_bf16(af[mi], bfr, acc[mi][ni], 0, 0, 0);
    }
  }

  int growb = m0 + wm * 64;
  int gcolb = n0 + wn * 64;
  if (mat == 2) {
    // V: write transposed VT[(b*H+h)*64+d][s]
#pragma unroll
    for (int mi = 0; mi < 4; mi++) {
      int row0 = growb + mi * 16 + quad * 4;
      int bb_ = row0 >> 11, sp = row0 & 2047;
#pragma unroll
      for (int ni = 0; ni < 4; ni++) {
        int gcol = gcolb + ni * 16 + c15;
        float bias = bv[gcol];
        int hh = gcol >> 6, dd = gcol & 63;
        f32x4 v = acc[mi][ni];
        ushort4 o = make_ushort4(f2bf(v[0] + bias), f2bf(v[1] + bias),
                                 f2bf(v[2] + bias), f2bf(v[3] + bias));
        *(ushort4*)(VT + ((size_t)((bb_ * HH + hh) * 64 + dd)) * SS + sp) = o;
      }
    }
  } else {
    // Q / K: bias + rotary via cs table; each wave's 64 cols = exactly one head,
    // rotary pair (d, d+32) = acc frags (ni, ni+2), same lane.
    unsigned short* Out = (mat == 0) ? Qr : Kr;
    const float* bias = (mat == 0) ? bq : bk;
    float qs = (mat == 0) ? 0.18033688011112042f : 1.0f;  // 0.125*log2(e) for Q
#pragma unroll
    for (int mi = 0; mi < 4; mi++) {
      int row0 = growb + mi * 16 + quad * 4;
#pragma unroll
      for (int ni = 0; ni < 2; ni++) {
        int gcol_lo = gcolb + ni * 16 + c15;      // d in [0,32) within head
        int gcol_hi = gcol_lo + 32;
        float blo = bias[gcol_lo], bhi = bias[gcol_hi];
        int d = ni * 16 + c15;
        f32x4 lo = acc[mi][ni], hi = acc[mi][ni + 2];
#pragma unroll
        for (int r = 0; r < 4; r++) {
          int grow = row0 + r;
          float2 cv = cs[(size_t)(grow & 2047) * 32 + d];
          float xl = (lo[r] + blo) * qs, xh = (hi[r] + bhi) * qs;
          Out[(size_t)grow * DD + gcol_lo] = f2bf(xl * cv.x - xh * cv.y);
          Out[(size_t)grow * DD + gcol_hi] = f2bf(xh * cv.x + xl * cv.y);
        }
      }
    }
  }
}

// ---- flash attention v11: 16x16x32 swapped-operand path, in-register P, ----
// ---- DETERMINISTIC truncation pack (no cvt_pk asm), no LDS in main loop ----
// Postmortem of v7/v8/v9 (all ~3e-2 absmax): the one shared unverified
// primitive was inline-asm v_cvt_pk_bf16_f32; if its convention is S0->high,
// every P dword is pair-swapped -> PV pairs P[k] with V[k^1] (l unaffected,
// it's a commutative sum) == the observed signature.  v11 packs with explicit
// bit ops (truncation, v6-precedent): element0 = f2u(p0)>>16 (low half),
// element1 = f2u(p1)&0xffff0000 (high half).  Zero unverified primitives:
// C/D map m89/m91; A-map==B-map pinned by v6's passing QK; V key-permutation
// is a bijection cancelling positionally against P's.
// Swapped QK^T: slo/shi = mfma(K, Q) -> lane (q=c15, quad) holds
// P[kpos = quad*4+r (+16 for shi)][q].  Packed lane-locally into the PV
// A-frag (element j <-> key rho(quad,j) = j<4 ? 4q+j : 16+4q+j-4); V's B-frag
// loaded with the SAME rho (two ushort4 at s-offsets 4*quad, 16+4*quad).
// l summed on the VALU from the TRUNCATED P words (numerator-consistent) +
// quad butterfly.  K/V double-buffered by t-unroll-2; Q in registers.
// No waves_per_eu forcing (v10: forced cap -> 820 MB/dispatch scratch spill).
__global__ __launch_bounds__(256)
void attn_kernel(
    const unsigned short* __restrict__ Qr, const unsigned short* __restrict__ Kr,
    const unsigned short* __restrict__ VT, float* __restrict__ out) {
  __shared__ __align__(16) float Obuf[64 * 65];         // 16.6 KB
  __shared__ float Lbuf[64];
  int bx = blockIdx.x;             // bx = qt*40 + bh; head pinned to one XCD (40%8==0)
  int bh = bx % 40, qtb = bx / 40;
  int b = bh / HH, h = bh % HH;
  int tid = threadIdx.x;
  int lane = tid & 63, w = tid >> 6;
  int c15 = lane & 15, quad = lane >> 4;
  int q0 = qtb * 64;

  // Q fragments in registers (B-operand: n=c15=q_local, k(d)=quad*8+j per 32-chunk)
  const unsigned short* Qb = Qr + (size_t)(b * SS + q0 + c15) * DD + h * 64 + quad * 8;
  bf16x8 qf[4][2];
#pragma unroll
  for (int qb = 0; qb < 4; qb++)
#pragma unroll
    for (int c = 0; c < 2; c++)
      qf[qb][c] = *(const bf16x8*)(Qb + (size_t)(qb * 16) * DD + c * 32);

  // K A-frag base: row(kpos)=c15, k(d)=quad*8+j; kb=0,1 adds 16*DD
  const unsigned short* Kp = Kr + (size_t)(b * SS + w * 32 + c15) * DD + h * 64 + quad * 8;
  // V B-frag base (permuted keys): elem j <- s = (j<4 ? 4*quad+j : 16+4*quad+j-4)
  const unsigned short* Vp = VT + (size_t)(bh * 64 + c15) * SS + w * 32 + quad * 4;

  union bfrag { ushort4 s[2]; bf16x8 v; };

  f32x4 of[4][4] = {};     // [qb][nio]: O[q=qb*16+quad*4+r][d=nio*16+c15]
  float ol[4] = {};        // per-qb partial l (this lane's 8 keys per tile)

#define LOADK(KF, TT)                                                         \
  {                                                                           \
    _Pragma("unroll")                                                         \
    for (int kb = 0; kb < 2; kb++)                                            \
      _Pragma("unroll")                                                       \
      for (int c = 0; c < 2; c++)                                             \
        KF[kb][c] = *(const bf16x8*)(Kp + (size_t)(TT) * (128 * DD) +         \
                                     (size_t)(kb * 16) * DD + c * 32);        \
  }
#define LOADV(VF, TT)                                                         \
  {                                                                           \
    _Pragma("unroll")                                                         \
    for (int nio = 0; nio < 4; nio++) {                                       \
      VF[nio].s[0] = *(const ushort4*)(Vp + (size_t)nio * (16 * SS) + (TT) * 128);      \
      VF[nio].s[1] = *(const ushort4*)(Vp + (size_t)nio * (16 * SS) + (TT) * 128 + 16); \
    }                                                                         \
  }
  // One 32-key tile: per qb: QK^T (4 mfma) -> exp2 -> trunc-pack -> PV (4 mfma).
#define TILE(KF, VF)                                                          \
  {                                                                           \
    _Pragma("unroll")                                                         \
    for (int qb = 0; qb < 4; qb++) {                                          \
      f32x4 slo = {}, shi = {};                                               \
      _Pragma("unroll")                                                       \
      for (int c = 0; c < 2; c++) {                                           \
        slo = __builtin_amdgcn_mfma_f32_16x16x32_bf16(KF[0][c], qf[qb][c], slo, 0, 0, 0); \
        shi = __builtin_amdgcn_mfma_f32_16x16x32_bf16(KF[1][c], qf[qb][c], shi, 0, 0, 0); \
      }                                                                       \
      unsigned e0 = f2u(__builtin_amdgcn_exp2f(slo[0]));                      \
      unsigned e1 = f2u(__builtin_amdgcn_exp2f(slo[1]));                      \
      unsigned e2 = f2u(__builtin_amdgcn_exp2f(slo[2]));                      \
      unsigned e3 = f2u(__builtin_amdgcn_exp2f(slo[3]));                      \
      unsigned e4 = f2u(__builtin_amdgcn_exp2f(shi[0]));                      \
      unsigned e5 = f2u(__builtin_amdgcn_exp2f(shi[1]));                      \
      unsigned e6 = f2u(__builtin_amdgcn_exp2f(shi[2]));                      \
      unsigned e7 = f2u(__builtin_amdgcn_exp2f(shi[3]));                      \
      union { unsigned u[4]; bf16x8 v; } af;                                  \
      af.u[0] = (e1 & 0xffff0000u) | (e0 >> 16);   /* elem0=slo0, elem1=slo1 */ \
      af.u[1] = (e3 & 0xffff0000u) | (e2 >> 16);                              \
      af.u[2] = (e5 & 0xffff0000u) | (e4 >> 16);                              \
      af.u[3] = (e7 & 0xffff0000u) | (e6 >> 16);                              \
      /* l from the TRUNCATED P words: consistent with the PV numerator */    \
      ol[qb] += u2f(e0 & 0xffff0000u) + u2f(e1 & 0xffff0000u)                 \
              + u2f(e2 & 0xffff0000u) + u2f(e3 & 0xffff0000u)                 \
              + u2f(e4 & 0xffff0000u) + u2f(e5 & 0xffff0000u)                 \
              + u2f(e6 & 0xffff0000u) + u2f(e7 & 0xffff0000u);                \
      _Pragma("unroll")                                                       \
      for (int nio = 0; nio < 4; nio++)                                       \
        of[qb][nio] = __builtin_amdgcn_mfma_f32_16x16x32_bf16(af.v, VF[nio].v, \
                                                              of[qb][nio], 0, 0, 0); \
    }                                                                         \
  }

  bf16x8 kfA[2][2], kfB[2][2];
  bfrag vfA[4], vfB[4];
  LOADK(kfA, 0)
  LOADV(vfA, 0)

  for (int t = 0; t < 16; t += 2) {
    LOADK(kfB, t + 1)
    LOADV(vfB, t + 1)
    TILE(kfA, vfA)
    if (t + 2 < 16) {
      LOADK(kfA, t + 2)
      LOADV(vfA, t + 2)
    }
    TILE(kfB, vfB)
  }
#undef LOADK
#undef LOADV
#undef TILE

  // l: butterfly over the two quad bits -> every lane holds the full quad-sum
  float lt[4];
#pragma unroll
  for (int qb = 0; qb < 4; qb++) {
    float v = ol[qb];
    v += __shfl_xor(v, 16);
    v += __shfl_xor(v, 32);
    lt[qb] = v;
  }

  // cross-wave reduction of O and l (serialized passes)
  for (int pass = 0; pass < 4; pass++) {
    if (w == pass) {
#pragma unroll
      for (int qb = 0; qb < 4; qb++) {
#pragma unroll
        for (int nio = 0; nio < 4; nio++)
#pragma unroll
          for (int r = 0; r < 4; r++) {
            int q = qb * 16 + quad * 4 + r;
            int d = nio * 16 + c15;
            if (pass == 0) Obuf[q * 65 + d] = of[qb][nio][r];
            else           Obuf[q * 65 + d] += of[qb][nio][r];
          }
        if (quad == 0) {
          if (pass == 0) Lbuf[qb * 16 + c15] = lt[qb];
          else           Lbuf[qb * 16 + c15] += lt[qb];
        }
      }
    }
    __syncthreads();
  }

  // epilogue: each wave writes 16 q-rows; lane covers 16 consecutive d
  {
    int row = w * 16 + (lane >> 2);
    int col0 = (lane & 3) * 16;
    float invl = 1.0f / Lbuf[row];
    float* op = out + (size_t)(b * SS + q0 + row) * DD + h * 64 + col0;
    const float* ob = Obuf + row * 65 + col0;
#pragma unroll
    for (int j = 0; j < 4; j++) {
      float4 v = make_float4(ob[j * 4 + 0] * invl, ob[j * 4 + 1] * invl,
                             ob[j * 4 + 2] * invl, ob[j * 4 + 3] * invl);
      *(float4*)(op + j * 4) = v;
    }
  }
}

extern "C" void kernel_launch(void* const* d_in, const int* in_sizes, int n_in,
                              void* d_out, int out_size, void* d_ws, size_t ws_size,
                              hipStream_t stream) {
  (void)in_sizes; (void)n_in; (void)out_size; (void)ws_size;
  const float* X  = (const float*)d_in[0];
  const float* Wq = (const float*)d_in[1];
  const float* bq = (const float*)d_in[2];
  const float* Wk = (const float*)d_in[3];
  const float* bk = (const float*)d_in[4];
  const float* Wv = (const float*)d_in[5];
  const float* bv = (const float*)d_in[6];
  char* ws = (char*)d_ws;
  unsigned short* Xb  = (unsigned short*)(ws);                 // 4096x1280 bf16
  unsigned short* WT  = (unsigned short*)(ws + 10485760);      // 3x1280x1280 bf16 (transposed)
  unsigned short* Qr  = (unsigned short*)(ws + 20316160);      // 4096x1280 bf16 (rotary'd, scaled)
  unsigned short* Kr  = (unsigned short*)(ws + 30801920);      // 4096x1280 bf16 (rotary'd)
  unsigned short* VTt = (unsigned short*)(ws + 41287680);      // [40][64][2048] bf16
  float2* cstab       = (float2*)(ws + 51773440);              // 2048x32 float2
  hipLaunchKernelGGL(prep_kernel, dim3(7616), dim3(256), 0, stream, X, Wq, Wk, Wv, Xb, WT, cstab);
  hipLaunchKernelGGL(qkv_gemm_kernel, dim3(960), dim3(256), 0, stream, Xb, WT, bq, bk, bv, cstab, Qr, Kr, VTt);
  hipLaunchKernelGGL(attn_kernel, dim3(1280), dim3(256), 0, stream, Qr, Kr, VTt, (float*)d_out);
}

// Round 6
// 282.438 us; speedup vs baseline: 1.5498x; 1.0631x over previous
//
#include <hip/hip_runtime.h>

#define DD 1280
#define SS 2048
#define HH 20

typedef __bf16 bf16x8 __attribute__((ext_vector_type(8)));
typedef float f32x4 __attribute__((ext_vector_type(4)));

typedef __attribute__((address_space(3))) unsigned int lds_uint;
typedef __attribute__((address_space(1))) unsigned int glb_uint;
#define GLL16(g, l) __builtin_amdgcn_global_load_lds((const glb_uint*)(g), (lds_uint*)(l), 16, 0, 0)

__device__ __forceinline__ unsigned short f2bf(float f) {
  union { float f; unsigned u; } v; v.f = f;
  unsigned r = v.u + 0x7fffu + ((v.u >> 16) & 1u);
  return (unsigned short)(r >> 16);
}
__device__ __forceinline__ unsigned f2u(float f) {
  union { float f; unsigned u; } v; v.f = f; return v.u;
}
__device__ __forceinline__ float u2f(unsigned x) {
  union { unsigned u; float f; } v; v.u = x; return v.f;
}

// ---- prep: cast X to bf16; transpose-cast W -> WT[n][k]; rotary cos/sin table ----
__global__ __launch_bounds__(256) void prep_kernel(
    const float* __restrict__ X, const float* __restrict__ Wq,
    const float* __restrict__ Wk, const float* __restrict__ Wv,
    unsigned short* __restrict__ Xb, unsigned short* __restrict__ WT,
    float2* __restrict__ cs) {
  __shared__ unsigned short tile[32][33];
  int bid = blockIdx.x, tid = threadIdx.x;
  if (bid < 2560) {
    size_t base = (size_t)bid * 2048 + (size_t)tid * 8;
    const float4* xin = (const float4*)(X + base);
    float4 a = xin[0], c = xin[1];
    ushort4 o0 = make_ushort4(f2bf(a.x), f2bf(a.y), f2bf(a.z), f2bf(a.w));
    ushort4 o1 = make_ushort4(f2bf(c.x), f2bf(c.y), f2bf(c.z), f2bf(c.w));
    *(ushort4*)(Xb + base) = o0;
    *(ushort4*)(Xb + base + 4) = o1;
  } else if (bid < 7360) {
    int wb = bid - 2560;          // 3 * 1600 tiles of 32x32
    int mat = wb / 1600;
    int t = wb % 1600;
    int tn = t % 40, tk = t / 40;
    const float* W = (mat == 0) ? Wq : ((mat == 1) ? Wk : Wv);
    int k0 = tk * 32, n0 = tn * 32;
    int tc = tid & 31, tr = tid >> 5;
#pragma unroll
    for (int i = 0; i < 4; i++) {
      int kl = tr + i * 8;
      tile[kl][tc] = f2bf(W[(size_t)(k0 + kl) * DD + n0 + tc]);
    }
    __syncthreads();
    unsigned short* out = WT + (size_t)mat * DD * DD;
#pragma unroll
    for (int i = 0; i < 4; i++) {
      int nl = tr + i * 8;
      out[(size_t)(n0 + nl) * DD + k0 + tc] = tile[tc][nl];
    }
  } else {
    // rotary table: cs[sp][j] = (cos, sin)(sp * 10000^(-j/32)), 2048 x 32
    int idx = (bid - 7360) * 256 + tid;     // 256 blocks -> 65536 entries
    int sp = idx >> 5, j = idx & 31;
    float invf = exp2f(-(float)j * 0.41524101186092034f);
    float ang = (float)sp * invf;
    cs[idx] = make_float2(cosf(ang), sinf(ang));
  }
}

// ---- QKV GEMM (m97 structure) + fused bias + rotary (table) epilogue ----
// Q additionally scaled by HD^-0.5 * log2(e) so attention can use exp2 directly.
__global__ __launch_bounds__(256) void qkv_gemm_kernel(
    const unsigned short* __restrict__ Xb, const unsigned short* __restrict__ WT,
    const float* __restrict__ bq, const float* __restrict__ bk, const float* __restrict__ bv,
    const float2* __restrict__ cs,
    unsigned short* __restrict__ Qr, unsigned short* __restrict__ Kr,
    unsigned short* __restrict__ VT) {
  __shared__ __align__(16) unsigned short As[128 * 32];
  __shared__ __align__(16) unsigned short Bs[128 * 32];
  int bx = blockIdx.x;            // 3 * 32 * 10
  int mat = bx / 320;
  int r0 = bx % 320;
  int tm = r0 / 10, tn = r0 % 10;
  int m0 = tm * 128, n0 = tn * 128;
  int tid = threadIdx.x;
  int lane = tid & 63, wave = tid >> 6;
  int c15 = lane & 15, quad = lane >> 4;
  int wm = wave >> 1, wn = wave & 1;
  const unsigned short* Wm = WT + (size_t)mat * DD * DD;

  int rowA = tid >> 2;
  int c8 = (tid & 3) * 8;
  const unsigned short* gA0 = Xb + (size_t)(m0 + rowA) * DD + c8;
  const unsigned short* gA1 = gA0 + (size_t)64 * DD;
  const unsigned short* gB0 = Wm + (size_t)(n0 + rowA) * DD + c8;
  const unsigned short* gB1 = gB0 + (size_t)64 * DD;
  unsigned short* ldsA0 = As + wave * 512;          // rows 0..63
  unsigned short* ldsA1 = As + 2048 + wave * 512;   // rows 64..127
  unsigned short* ldsB0 = Bs + wave * 512;
  unsigned short* ldsB1 = Bs + 2048 + wave * 512;

  f32x4 acc[4][4] = {};

  for (int kk = 0; kk < DD; kk += 32) {
    __syncthreads();
    GLL16(gA0 + kk, ldsA0);
    GLL16(gA1 + kk, ldsA1);
    GLL16(gB0 + kk, ldsB0);
    GLL16(gB1 + kk, ldsB1);
    __syncthreads();
    bf16x8 af[4];
#pragma unroll
    for (int mi = 0; mi < 4; mi++)
      af[mi] = *(const bf16x8*)(As + (wm * 64 + mi * 16 + c15) * 32 + quad * 8);
#pragma unroll
    for (int ni = 0; ni < 4; ni++) {
      bf16x8 bfr = *(const bf16x8*)(Bs + (wn * 64 + ni * 16 + c15) * 32 + quad * 8);
#pragma unroll
      for (int mi = 0; mi < 4; mi++)
        acc[mi][ni] = __builtin_amdgcn_mfma_f32_16x16x32_bf16(af[mi], bfr, acc[mi][ni], 0, 0, 0);
    }
  }

  int growb = m0 + wm * 64;
  int gcolb = n0 + wn * 64;
  if (mat == 2) {
    // V: write transposed VT[(b*H+h)*64+d][s]
#pragma unroll
    for (int mi = 0; mi < 4; mi++) {
      int row0 = growb + mi * 16 + quad * 4;
      int bb_ = row0 >> 11, sp = row0 & 2047;
#pragma unroll
      for (int ni = 0; ni < 4; ni++) {
        int gcol = gcolb + ni * 16 + c15;
        float bias = bv[gcol];
        int hh = gcol >> 6, dd = gcol & 63;
        f32x4 v = acc[mi][ni];
        ushort4 o = make_ushort4(f2bf(v[0] + bias), f2bf(v[1] + bias),
                                 f2bf(v[2] + bias), f2bf(v[3] + bias));
        *(ushort4*)(VT + ((size_t)((bb_ * HH + hh) * 64 + dd)) * SS + sp) = o;
      }
    }
  } else {
    // Q / K: bias + rotary via cs table; each wave's 64 cols = exactly one head,
    // rotary pair (d, d+32) = acc frags (ni, ni+2), same lane.
    unsigned short* Out = (mat == 0) ? Qr : Kr;
    const float* bias = (mat == 0) ? bq : bk;
    float qs = (mat == 0) ? 0.18033688011112042f : 1.0f;  // 0.125*log2(e) for Q
#pragma unroll
    for (int mi = 0; mi < 4; mi++) {
      int row0 = growb + mi * 16 + quad * 4;
#pragma unroll
      for (int ni = 0; ni < 2; ni++) {
        int gcol_lo = gcolb + ni * 16 + c15;      // d in [0,32) within head
        int gcol_hi = gcol_lo + 32;
        float blo = bias[gcol_lo], bhi = bias[gcol_hi];
        int d = ni * 16 + c15;
        f32x4 lo = acc[mi][ni], hi = acc[mi][ni + 2];
#pragma unroll
        for (int r = 0; r < 4; r++) {
          int grow = row0 + r;
          float2 cv = cs[(size_t)(grow & 2047) * 32 + d];
          float xl = (lo[r] + blo) * qs, xh = (hi[r] + bhi) * qs;
          Out[(size_t)grow * DD + gcol_lo] = f2bf(xl * cv.x - xh * cv.y);
          Out[(size_t)grow * DD + gcol_hi] = f2bf(xh * cv.x + xl * cv.y);
        }
      }
    }
  }
}

// ---- flash attention v12: v11 numerics (verified) + register diet for occupancy ----
// v11 postmortem: passed (absmax 4.9e-4) but 149.7us: Occupancy 11%, MfmaUtil
// 11.3, VALUBusy 24.5, HBM 4% -> latency-bound with ~1 wave/SIMD; operand
// state (qf 32 + kf dbuf 32 + vf dbuf 32 = 96 arch on top of 68 acc) pushed
// the allocation over the 2-waves boundary.  v12 cuts state, numerics
// bit-identical:
//  * Q -> LDS via global_load_lds (v10-verified staging/slot layout), read
//    on demand as conflict-free ds_read_b128 (lane*16B).  -32 arch regs.
//  * V single-buffered: vf's last consumer is this tile's final PV; the
//    t+1 prefetch issues right after the TILE (WAR-safe: in-order issue
//    after all consumers) and is covered by the next tile's QK+exp2 phase
//    plus TLP.  -16 arch regs.  K stays double-buffered (consumed FIRST in
//    each tile, so single-buffering K would leave no latency cover).
//  * l-sum as a 3-level tree instead of an 8-deep serial add chain.
// Target ~160 total regs -> 3 waves/SIMD naturally; NO waves_per_eu forcing
// (v10: forced cap caused an 820 MB/dispatch spill).  Spill tripwire:
// WRITE_SIZE above the 20.5 MB output.
__global__ __launch_bounds__(256)
void attn_kernel(
    const unsigned short* __restrict__ Qr, const unsigned short* __restrict__ Kr,
    const unsigned short* __restrict__ VT, float* __restrict__ out) {
  __shared__ __align__(16) unsigned short Qlds[512 * 8];  // 8 KB: Q frags (qb,c,lane)
  __shared__ __align__(16) float Obuf[64 * 65];           // 16.6 KB
  __shared__ float Lbuf[64];
  int bx = blockIdx.x;             // bx = qt*40 + bh; head pinned to one XCD (40%8==0)
  int bh = bx % 40, qtb = bx / 40;
  int b = bh / HH, h = bh % HH;
  int tid = threadIdx.x;
  int lane = tid & 63, w = tid >> 6;
  int c15 = lane & 15, quad = lane >> 4;
  int q0 = qtb * 64;

  // stage Q fragments (block-uniform) into LDS via global_load_lds.
  // wave w stages (qb = w>>1, c = w&1) and (qb = 2+(w>>1), c = w&1);
  // slot ((qb*2+c)*64 + lane) holds Q[q0+qb*16+(lane&15)][h*64+c*32+(lane>>4)*8+j]
  // == v11's qf[qb][c] for that lane.  (Layout harness-verified in v10.)
  {
    int qbs = w >> 1, cs_ = w & 1;
    const unsigned short* s0 = Qr + (size_t)(b * SS + q0 + qbs * 16 + c15) * DD
                               + h * 64 + cs_ * 32 + quad * 8;
    GLL16(s0, Qlds + (size_t)(w * 64) * 8);
    GLL16(s0 + (size_t)32 * DD, Qlds + (size_t)((4 + w) * 64) * 8);
  }

  // K A-frag base: row(kpos)=c15, k(d)=quad*8+j; kb=0,1 adds 16*DD
  const unsigned short* Kp = Kr + (size_t)(b * SS + w * 32 + c15) * DD + h * 64 + quad * 8;
  // V B-frag base (permuted keys): elem j <- s = (j<4 ? 4*quad+j : 16+4*quad+j-4)
  const unsigned short* Vp = VT + (size_t)(bh * 64 + c15) * SS + w * 32 + quad * 4;

  union bfrag { ushort4 s[2]; bf16x8 v; };

  f32x4 of[4][4] = {};     // [qb][nio]: O[q=qb*16+quad*4+r][d=nio*16+c15]
  float ol[4] = {};        // per-qb partial l (this lane's 8 keys per tile)

#define LOADK(KF, TT)                                                         \
  {                                                                           \
    _Pragma("unroll")                                                         \
    for (int kb = 0; kb < 2; kb++)                                            \
      _Pragma("unroll")                                                       \
      for (int c = 0; c < 2; c++)                                             \
        KF[kb][c] = *(const bf16x8*)(Kp + (size_t)(TT) * (128 * DD) +         \
                                     (size_t)(kb * 16) * DD + c * 32);        \
  }
#define LOADV(VF, TT)                                                         \
  {                                                                           \
    _Pragma("unroll")                                                         \
    for (int nio = 0; nio < 4; nio++) {                                       \
      VF[nio].s[0] = *(const ushort4*)(Vp + (size_t)nio * (16 * SS) + (TT) * 128);      \
      VF[nio].s[1] = *(const ushort4*)(Vp + (size_t)nio * (16 * SS) + (TT) * 128 + 16); \
    }                                                                         \
  }
  // One 32-key tile: per qb: QK^T (4 mfma, Q from LDS) -> exp2 -> trunc-pack
  // -> PV (4 mfma).  Identical arithmetic to v11 (verified).
#define TILE(KF, VF)                                                          \
  {                                                                           \
    _Pragma("unroll")                                                         \
    for (int qb = 0; qb < 4; qb++) {                                          \
      f32x4 slo = {}, shi = {};                                               \
      _Pragma("unroll")                                                       \
      for (int c = 0; c < 2; c++) {                                           \
        bf16x8 qv = *(const bf16x8*)(Qlds + ((qb * 2 + c) * 64 + lane) * 8);  \
        slo = __builtin_amdgcn_mfma_f32_16x16x32_bf16(KF[0][c], qv, slo, 0, 0, 0); \
        shi = __builtin_amdgcn_mfma_f32_16x16x32_bf16(KF[1][c], qv, shi, 0, 0, 0); \
      }                                                                       \
      unsigned e0 = f2u(__builtin_amdgcn_exp2f(slo[0]));                      \
      unsigned e1 = f2u(__builtin_amdgcn_exp2f(slo[1]));                      \
      unsigned e2 = f2u(__builtin_amdgcn_exp2f(slo[2]));                      \
      unsigned e3 = f2u(__builtin_amdgcn_exp2f(slo[3]));                      \
      unsigned e4 = f2u(__builtin_amdgcn_exp2f(shi[0]));                      \
      unsigned e5 = f2u(__builtin_amdgcn_exp2f(shi[1]));                      \
      unsigned e6 = f2u(__builtin_amdgcn_exp2f(shi[2]));                      \
      unsigned e7 = f2u(__builtin_amdgcn_exp2f(shi[3]));                      \
      union { unsigned u[4]; bf16x8 v; } af;                                  \
      af.u[0] = (e1 & 0xffff0000u) | (e0 >> 16);   /* elem0=slo0, elem1=slo1 */ \
      af.u[1] = (e3 & 0xffff0000u) | (e2 >> 16);                              \
      af.u[2] = (e5 & 0xffff0000u) | (e4 >> 16);                              \
      af.u[3] = (e7 & 0xffff0000u) | (e6 >> 16);                              \
      /* l from the TRUNCATED P words (numerator-consistent), tree-summed */  \
      {                                                                       \
        float s01 = u2f(e0 & 0xffff0000u) + u2f(e1 & 0xffff0000u);            \
        float s23 = u2f(e2 & 0xffff0000u) + u2f(e3 & 0xffff0000u);            \
        float s45 = u2f(e4 & 0xffff0000u) + u2f(e5 & 0xffff0000u);            \
        float s67 = u2f(e6 & 0xffff0000u) + u2f(e7 & 0xffff0000u);            \
        ol[qb] += (s01 + s23) + (s45 + s67);                                  \
      }                                                                       \
      _Pragma("unroll")                                                       \
      for (int nio = 0; nio < 4; nio++)                                       \
        of[qb][nio] = __builtin_amdgcn_mfma_f32_16x16x32_bf16(af.v, VF[nio].v, \
                                                              of[qb][nio], 0, 0, 0); \
    }                                                                         \
  }

  bf16x8 kfA[2][2], kfB[2][2];
  bfrag vf[4];
  LOADK(kfA, 0)
  LOADV(vf, 0)

  __syncthreads();   // Qlds ready (drains global_load_lds; also t=0 K/V)

  for (int t = 0; t < 16; t += 2) {
    LOADK(kfB, t + 1)
    TILE(kfA, vf)                       // tile t (consumes vf)
    LOADV(vf, t + 1)                    // prefetch V for t+1 after last consumer
    if (t + 2 < 16) LOADK(kfA, t + 2)
    TILE(kfB, vf)                       // tile t+1
    {
      int tn = (t + 2 < 16) ? t + 2 : 15;   // clamped (dead at t=14 tail)
      LOADV(vf, tn)
    }
  }
#undef LOADK
#undef LOADV
#undef TILE

  // l: butterfly over the two quad bits -> every lane holds the full quad-sum
  float lt[4];
#pragma unroll
  for (int qb = 0; qb < 4; qb++) {
    float v = ol[qb];
    v += __shfl_xor(v, 16);
    v += __shfl_xor(v, 32);
    lt[qb] = v;
  }

  // cross-wave reduction of O and l (serialized passes)
  for (int pass = 0; pass < 4; pass++) {
    if (w == pass) {
#pragma unroll
      for (int qb = 0; qb < 4; qb++) {
#pragma unroll
        for (int nio = 0; nio < 4; nio++)
#pragma unroll
          for (int r = 0; r < 4; r++) {
            int q = qb * 16 + quad * 4 + r;
            int d = nio * 16 + c15;
            if (pass == 0) Obuf[q * 65 + d] = of[qb][nio][r];
            else           Obuf[q * 65 + d] += of[qb][nio][r];
          }
        if (quad == 0) {
          if (pass == 0) Lbuf[qb * 16 + c15] = lt[qb];
          else           Lbuf[qb * 16 + c15] += lt[qb];
        }
      }
    }
    __syncthreads();
  }

  // epilogue: each wave writes 16 q-rows; lane covers 16 consecutive d
  {
    int row = w * 16 + (lane >> 2);
    int col0 = (lane & 3) * 16;
    float invl = 1.0f / Lbuf[row];
    float* op = out + (size_t)(b * SS + q0 + row) * DD + h * 64 + col0;
    const float* ob = Obuf + row * 65 + col0;
#pragma unroll
    for (int j = 0; j < 4; j++) {
      float4 v = make_float4(ob[j * 4 + 0] * invl, ob[j * 4 + 1] * invl,
                             ob[j * 4 + 2] * invl, ob[j * 4 + 3] * invl);
      *(float4*)(op + j * 4) = v;
    }
  }
}

extern "C" void kernel_launch(void* const* d_in, const int* in_sizes, int n_in,
                              void* d_out, int out_size, void* d_ws, size_t ws_size,
                              hipStream_t stream) {
  (void)in_sizes; (void)n_in; (void)out_size; (void)ws_size;
  const float* X  = (const float*)d_in[0];
  const float* Wq = (const float*)d_in[1];
  const float* bq = (const float*)d_in[2];
  const float* Wk = (const float*)d_in[3];
  const float* bk = (const float*)d_in[4];
  const float* Wv = (const float*)d_in[5];
  const float* bv = (const float*)d_in[6];
  char* ws = (char*)d_ws;
  unsigned short* Xb  = (unsigned short*)(ws);                 // 4096x1280 bf16
  unsigned short* WT  = (unsigned short*)(ws + 10485760);      // 3x1280x1280 bf16 (transposed)
  unsigned short* Qr  = (unsigned short*)(ws + 20316160);      // 4096x1280 bf16 (rotary'd, scaled)
  unsigned short* Kr  = (unsigned short*)(ws + 30801920);      // 4096x1280 bf16 (rotary'd)
  unsigned short* VTt = (unsigned short*)(ws + 41287680);      // [40][64][2048] bf16
  float2* cstab       = (float2*)(ws + 51773440);              // 2048x32 float2
  hipLaunchKernelGGL(prep_kernel, dim3(7616), dim3(256), 0, stream, X, Wq, Wk, Wv, Xb, WT, cstab);
  hipLaunchKernelGGL(qkv_gemm_kernel, dim3(960), dim3(256), 0, stream, Xb, WT, bq, bk, bv, cstab, Qr, Kr, VTt);
  hipLaunchKernelGGL(attn_kernel, dim3(1280), dim3(256), 0, stream, Qr, Kr, VTt, (float*)d_out);
}

// Round 7
// 277.994 us; speedup vs baseline: 1.5746x; 1.0160x over previous
//
#include <hip/hip_runtime.h>

#define DD 1280
#define SS 2048
#define HH 20

typedef __bf16 bf16x8 __attribute__((ext_vector_type(8)));
typedef float f32x4 __attribute__((ext_vector_type(4)));

typedef __attribute__((address_space(3))) unsigned int lds_uint;
typedef __attribute__((address_space(1))) unsigned int glb_uint;
#define GLL16(g, l) __builtin_amdgcn_global_load_lds((const glb_uint*)(g), (lds_uint*)(l), 16, 0, 0)

__device__ __forceinline__ unsigned short f2bf(float f) {
  union { float f; unsigned u; } v; v.f = f;
  unsigned r = v.u + 0x7fffu + ((v.u >> 16) & 1u);
  return (unsigned short)(r >> 16);
}
__device__ __forceinline__ unsigned f2u(float f) {
  union { float f; unsigned u; } v; v.f = f; return v.u;
}

// ---- prep: cast X to bf16; transpose-cast W -> WT[n][k]; rotary cos/sin table ----
__global__ __launch_bounds__(256) void prep_kernel(
    const float* __restrict__ X, const float* __restrict__ Wq,
    const float* __restrict__ Wk, const float* __restrict__ Wv,
    unsigned short* __restrict__ Xb, unsigned short* __restrict__ WT,
    float2* __restrict__ cs) {
  __shared__ unsigned short tile[32][33];
  int bid = blockIdx.x, tid = threadIdx.x;
  if (bid < 2560) {
    size_t base = (size_t)bid * 2048 + (size_t)tid * 8;
    const float4* xin = (const float4*)(X + base);
    float4 a = xin[0], c = xin[1];
    ushort4 o0 = make_ushort4(f2bf(a.x), f2bf(a.y), f2bf(a.z), f2bf(a.w));
    ushort4 o1 = make_ushort4(f2bf(c.x), f2bf(c.y), f2bf(c.z), f2bf(c.w));
    *(ushort4*)(Xb + base) = o0;
    *(ushort4*)(Xb + base + 4) = o1;
  } else if (bid < 7360) {
    int wb = bid - 2560;          // 3 * 1600 tiles of 32x32
    int mat = wb / 1600;
    int t = wb % 1600;
    int tn = t % 40, tk = t / 40;
    const float* W = (mat == 0) ? Wq : ((mat == 1) ? Wk : Wv);
    int k0 = tk * 32, n0 = tn * 32;
    int tc = tid & 31, tr = tid >> 5;
#pragma unroll
    for (int i = 0; i < 4; i++) {
      int kl = tr + i * 8;
      tile[kl][tc] = f2bf(W[(size_t)(k0 + kl) * DD + n0 + tc]);
    }
    __syncthreads();
    unsigned short* out = WT + (size_t)mat * DD * DD;
#pragma unroll
    for (int i = 0; i < 4; i++) {
      int nl = tr + i * 8;
      out[(size_t)(n0 + nl) * DD + k0 + tc] = tile[tc][nl];
    }
  } else {
    // rotary table: cs[sp][j] = (cos, sin)(sp * 10000^(-j/32)), 2048 x 32
    int idx = (bid - 7360) * 256 + tid;     // 256 blocks -> 65536 entries
    int sp = idx >> 5, j = idx & 31;
    float invf = exp2f(-(float)j * 0.41524101186092034f);
    float ang = (float)sp * invf;
    cs[idx] = make_float2(cosf(ang), sinf(ang));
  }
}

// ---- QKV GEMM: m97 structure, BK 32->64 (halved barrier-drain count) ----
// Theory (r6): qkv ~= 135us ~= 300 TF; the 2-phase structure's stall is the
// per-K-step vmcnt(0)+barrier drain (40 of them at BK=32).  BK=64 stages the
// same bytes with HALF the barriers.  [128][64] rows are 128B -> naive reads
// would 16-way bank-conflict, so rule-#21 swizzle: linear LDS dest (GLL16
// constraint) + inverse-swizzled global SOURCE col ((l&7)^(l>>3)) + swizzled
// READ (col16 ^ (row&7)) -> 2-way (free).  Accumulation order bit-identical
// to BK=32 (c=0,1 == old kk, kk+32).  Epilogue unchanged.
__global__ __launch_bounds__(256) void qkv_gemm_kernel(
    const unsigned short* __restrict__ Xb, const unsigned short* __restrict__ WT,
    const float* __restrict__ bq, const float* __restrict__ bk, const float* __restrict__ bv,
    const float2* __restrict__ cs,
    unsigned short* __restrict__ Qr, unsigned short* __restrict__ Kr,
    unsigned short* __restrict__ VT) {
  __shared__ __align__(16) unsigned short As[128 * 64];
  __shared__ __align__(16) unsigned short Bs[128 * 64];
  int bx = blockIdx.x;            // 3 * 32 * 10
  int mat = bx / 320;
  int r0 = bx % 320;
  int tm = r0 / 10, tn = r0 % 10;
  int m0 = tm * 128, n0 = tn * 128;
  int tid = threadIdx.x;
  int lane = tid & 63, wave = tid >> 6;
  int c15 = lane & 15, quad = lane >> 4;
  int wm = wave >> 1, wn = wave & 1;
  const unsigned short* Wm = WT + (size_t)mat * DD * DD;

  // staging: wave w, pass p covers rows p*32 + w*8 + (lane>>3); lane's 16B
  // lands linearly at LDS 16B-slot (row*8 + (lane&7)); source col-group is
  // the inverse swizzle (lane&7)^(lane>>3) so reads can use col16^(row&7).
  int srow = lane >> 3;
  int scol = ((lane & 7) ^ srow) * 8;
  const unsigned short* gA = Xb + (size_t)(m0 + wave * 8 + srow) * DD + scol;
  const unsigned short* gB = Wm + (size_t)(n0 + wave * 8 + srow) * DD + scol;
  unsigned short* ldsA = As + (wave * 8) * 64;   // + p*32*64; wave-uniform base
  unsigned short* ldsB = Bs + (wave * 8) * 64;

  f32x4 acc[4][4] = {};

  for (int kk = 0; kk < DD; kk += 64) {
    __syncthreads();
#pragma unroll
    for (int p = 0; p < 4; p++) {
      GLL16(gA + (size_t)(p * 32) * DD + kk, ldsA + p * 32 * 64);
      GLL16(gB + (size_t)(p * 32) * DD + kk, ldsB + p * 32 * 64);
    }
    __syncthreads();
#pragma unroll
    for (int c = 0; c < 2; c++) {
      bf16x8 af[4];
#pragma unroll
      for (int mi = 0; mi < 4; mi++) {
        int row = wm * 64 + mi * 16 + c15;
        af[mi] = *(const bf16x8*)(As + row * 64 + (((c * 4 + quad) ^ (row & 7)) * 8));
      }
#pragma unroll
      for (int ni = 0; ni < 4; ni++) {
        int rowb = wn * 64 + ni * 16 + c15;
        bf16x8 bfr = *(const bf16x8*)(Bs + rowb * 64 + (((c * 4 + quad) ^ (rowb & 7)) * 8));
#pragma unroll
        for (int mi = 0; mi < 4; mi++)
          acc[mi][ni] = __builtin_amdgcn_mfma_f32_16x16x32_bf16(af[mi], bfr, acc[mi][ni], 0, 0, 0);
      }
    }
  }

  int growb = m0 + wm * 64;
  int gcolb = n0 + wn * 64;
  if (mat == 2) {
    // V: write transposed VT[(b*H+h)*64+d][s]
#pragma unroll
    for (int mi = 0; mi < 4; mi++) {
      int row0 = growb + mi * 16 + quad * 4;
      int bb_ = row0 >> 11, sp = row0 & 2047;
#pragma unroll
      for (int ni = 0; ni < 4; ni++) {
        int gcol = gcolb + ni * 16 + c15;
        float bias = bv[gcol];
        int hh = gcol >> 6, dd = gcol & 63;
        f32x4 v = acc[mi][ni];
        ushort4 o = make_ushort4(f2bf(v[0] + bias), f2bf(v[1] + bias),
                                 f2bf(v[2] + bias), f2bf(v[3] + bias));
        *(ushort4*)(VT + ((size_t)((bb_ * HH + hh) * 64 + dd)) * SS + sp) = o;
      }
    }
  } else {
    // Q / K: bias + rotary via cs table; each wave's 64 cols = exactly one head,
    // rotary pair (d, d+32) = acc frags (ni, ni+2), same lane.
    unsigned short* Out = (mat == 0) ? Qr : Kr;
    const float* bias = (mat == 0) ? bq : bk;
    float qs = (mat == 0) ? 0.18033688011112042f : 1.0f;  // 0.125*log2(e) for Q
#pragma unroll
    for (int mi = 0; mi < 4; mi++) {
      int row0 = growb + mi * 16 + quad * 4;
#pragma unroll
      for (int ni = 0; ni < 2; ni++) {
        int gcol_lo = gcolb + ni * 16 + c15;      // d in [0,32) within head
        int gcol_hi = gcol_lo + 32;
        float blo = bias[gcol_lo], bhi = bias[gcol_hi];
        int d = ni * 16 + c15;
        f32x4 lo = acc[mi][ni], hi = acc[mi][ni + 2];
#pragma unroll
        for (int r = 0; r < 4; r++) {
          int grow = row0 + r;
          float2 cv = cs[(size_t)(grow & 2047) * 32 + d];
          float xl = (lo[r] + blo) * qs, xh = (hi[r] + bhi) * qs;
          Out[(size_t)grow * DD + gcol_lo] = f2bf(xl * cv.x - xh * cv.y);
          Out[(size_t)grow * DD + gcol_hi] = f2bf(xh * cv.x + xl * cv.y);
        }
      }
    }
  }
}

// ---- flash attention v13: v6 structure restored VERBATIM (96.5us, proven)
// + T5 s_setprio(1) around MFMA clusters only (m191: attn +4-7%; regime
// matches: 4 independent waves, no barriers in the t-loop).
// v11/v12 postmortem: swapped in-register-P path is correct but slower --
// the 64-reg accumulator keeps total allocation ~196 regardless of arch
// diet, so occupancy never improves while VALU work grows.  Reverted.
__device__ __forceinline__ void attn_load_frags(
    bf16x8 (&kf)[2][2], bf16x8 (&vf)[4],
    const unsigned short* Kt, const unsigned short* Vt, int c15, int quad) {
#pragma unroll
  for (int ni = 0; ni < 2; ni++)
#pragma unroll
    for (int kc = 0; kc < 2; kc++)
      kf[ni][kc] = *(const bf16x8*)(Kt + (size_t)(ni * 16 + c15) * DD + kc * 32 + quad * 8);
#pragma unroll
  for (int nio = 0; nio < 4; nio++)
    vf[nio] = *(const bf16x8*)(Vt + (size_t)(nio * 16 + c15) * SS + quad * 8);
}

__device__ __forceinline__ void attn_tile(
    const bf16x8 (&qf)[4][2], const bf16x8 (&kf)[2][2], const bf16x8 (&vf)[4],
    const bf16x8& ones, f32x4 (&of)[4][4], f32x4 (&ol)[4],
    unsigned short* Pw, int c15, int quad) {
  // S = Q K^T  (64q x 32k per wave)
  f32x4 sc[4][2] = {};
  __builtin_amdgcn_s_setprio(1);
#pragma unroll
  for (int ni = 0; ni < 2; ni++)
#pragma unroll
    for (int kc = 0; kc < 2; kc++)
#pragma unroll
      for (int mi = 0; mi < 4; mi++)
        sc[mi][ni] = __builtin_amdgcn_mfma_f32_16x16x32_bf16(qf[mi][kc], kf[ni][kc], sc[mi][ni], 0, 0, 0);
  __builtin_amdgcn_s_setprio(0);

  int pos_r = (quad + 2 * ((c15 >> 2) & 3) + (c15 & 3)) & 7;   // read-side swizzle

#define PROD(mi)                                                              \
  {                                                                           \
    _Pragma("unroll")                                                         \
    for (int ni = 0; ni < 2; ni++) {                                          \
      int kc8 = ni * 2 + (c15 >> 3);                                          \
      _Pragma("unroll")                                                       \
      for (int r = 0; r < 4; r++) {                                           \
        unsigned u = f2u(__builtin_amdgcn_exp2f(sc[mi][ni][r]));              \
        int q = (mi) * 16 + quad * 4 + r;                                     \
        int pos = (kc8 + 2 * quad + r) & 7;                                   \
        Pw[q * 64 + pos * 8 + (c15 & 7)] = (unsigned short)(u >> 16);         \
      }                                                                       \
    }                                                                         \
  }
#define CONS(mi)                                                              \
  {                                                                           \
    bf16x8 pf = *(const bf16x8*)(Pw + ((mi) * 16 + c15) * 64 + pos_r * 8);    \
    __builtin_amdgcn_s_setprio(1);                                            \
    _Pragma("unroll")                                                         \
    for (int nio = 0; nio < 4; nio++)                                         \
      of[mi][nio] = __builtin_amdgcn_mfma_f32_16x16x32_bf16(pf, vf[nio],      \
                                                            of[mi][nio], 0, 0, 0); \
    ol[mi] = __builtin_amdgcn_mfma_f32_16x16x32_bf16(pf, ones, ol[mi], 0, 0, 0); \
    __builtin_amdgcn_s_setprio(0);                                            \
  }

  PROD(0);
  PROD(1); CONS(0);
  PROD(2); CONS(1);
  PROD(3); CONS(2);
  CONS(3);
#undef PROD
#undef CONS
}

__global__ __launch_bounds__(256)
__attribute__((amdgpu_waves_per_eu(2, 4)))
void attn_kernel(
    const unsigned short* __restrict__ Qr, const unsigned short* __restrict__ Kr,
    const unsigned short* __restrict__ VT, float* __restrict__ out) {
  __shared__ __align__(16) unsigned short Pall[4 * 64 * 64];  // 32 KB: per-wave P strips
  __shared__ float Lbuf[64];
  int bx = blockIdx.x;             // bx = qt*40 + bh; head pinned to one XCD (40%8==0)
  int bh = bx % 40, qt = bx / 40;
  int b = bh / HH, h = bh % HH;
  int tid = threadIdx.x;
  int lane = tid & 63, w = tid >> 6;
  int c15 = lane & 15, quad = lane >> 4;
  int q0 = qt * 64;

  // Q frags direct from global (A-layout: lane m=c15, k=quad*8), kept in regs
  const unsigned short* Qbase = Qr + (size_t)(b * SS + q0) * DD + h * 64;
  bf16x8 qf[4][2];
#pragma unroll
  for (int mi = 0; mi < 4; mi++)
#pragma unroll
    for (int kc = 0; kc < 2; kc++)
      qf[mi][kc] = *(const bf16x8*)(Qbase + (size_t)(mi * 16 + c15) * DD + kc * 32 + quad * 8);

  const unsigned short* Kbase = Kr + (size_t)(b * SS + w * 32) * DD + h * 64;
  const unsigned short* Vbase = VT + (size_t)(bh * 64) * SS + w * 32;
  unsigned short* Pw = Pall + w * 4096;   // 64 rows x 64 shorts

  bf16x8 ones;
#pragma unroll
  for (int i = 0; i < 8; i++) ones[i] = (__bf16)1.0f;

  f32x4 of[4][4] = {};       // [mi][nio]
  f32x4 ol[4] = {};          // l via P*ones

  bf16x8 kfb[2][2][2], vfb[2][4];   // double-buffered K/V fragments
  attn_load_frags(kfb[0], vfb[0], Kbase, Vbase, c15, quad);

  for (int t = 0; t < 16; t += 2) {
    // issue t+1 loads into buf1 before computing buf0
    attn_load_frags(kfb[1], vfb[1],
                    Kbase + (size_t)((t + 1) * 128) * DD, Vbase + (t + 1) * 128,
                    c15, quad);
    attn_tile(qf, kfb[0], vfb[0], ones, of, ol, Pw, c15, quad);
    if (t + 2 < 16)
      attn_load_frags(kfb[0], vfb[0],
                      Kbase + (size_t)((t + 2) * 128) * DD, Vbase + (t + 2) * 128,
                      c15, quad);
    attn_tile(qf, kfb[1], vfb[1], ones, of, ol, Pw, c15, quad);
  }

  // all waves done with their P strips -> safe to overlay Obuf on Pall
  __syncthreads();
  float* Obuf = (float*)Pall;      // 64 x 65 floats = 16.6 KB of the 32 KB strip area

  // cross-wave reduction of O and l (serialized passes)
  for (int pass = 0; pass < 4; pass++) {
    if (w == pass) {
#pragma unroll
      for (int mi = 0; mi < 4; mi++)
#pragma unroll
        for (int nio = 0; nio < 4; nio++)
#pragma unroll
          for (int r = 0; r < 4; r++) {
            int q = mi * 16 + quad * 4 + r;
            int d = nio * 16 + c15;
            if (pass == 0) Obuf[q * 65 + d] = of[mi][nio][r];
            else           Obuf[q * 65 + d] += of[mi][nio][r];
          }
      if (c15 == 0) {
#pragma unroll
        for (int mi = 0; mi < 4; mi++)
#pragma unroll
          for (int r = 0; r < 4; r++) {
            int q = mi * 16 + quad * 4 + r;
            if (pass == 0) Lbuf[q] = ol[mi][r];
            else           Lbuf[q] += ol[mi][r];
          }
      }
    }
    __syncthreads();
  }

  // epilogue: each wave writes 16 q-rows; lane covers 16 consecutive d
  {
    int row = w * 16 + (lane >> 2);
    int col0 = (lane & 3) * 16;
    float invl = 1.0f / Lbuf[row];
    float* op = out + (size_t)(b * SS + q0 + row) * DD + h * 64 + col0;
    const float* ob = Obuf + row * 65 + col0;
#pragma unroll
    for (int j = 0; j < 4; j++) {
      float4 v = make_float4(ob[j * 4 + 0] * invl, ob[j * 4 + 1] * invl,
                             ob[j * 4 + 2] * invl, ob[j * 4 + 3] * invl);
      *(float4*)(op + j * 4) = v;
    }
  }
}

extern "C" void kernel_launch(void* const* d_in, const int* in_sizes, int n_in,
                              void* d_out, int out_size, void* d_ws, size_t ws_size,
                              hipStream_t stream) {
  (void)in_sizes; (void)n_in; (void)out_size; (void)ws_size;
  const float* X  = (const float*)d_in[0];
  const float* Wq = (const float*)d_in[1];
  const float* bq = (const float*)d_in[2];
  const float* Wk = (const float*)d_in[3];
  const float* bk = (const float*)d_in[4];
  const float* Wv = (const float*)d_in[5];
  const float* bv = (const float*)d_in[6];
  char* ws = (char*)d_ws;
  unsigned short* Xb  = (unsigned short*)(ws);                 // 4096x1280 bf16
  unsigned short* WT  = (unsigned short*)(ws + 10485760);      // 3x1280x1280 bf16 (transposed)
  unsigned short* Qr  = (unsigned short*)(ws + 20316160);      // 4096x1280 bf16 (rotary'd, scaled)
  unsigned short* Kr  = (unsigned short*)(ws + 30801920);      // 4096x1280 bf16 (rotary'd)
  unsigned short* VTt = (unsigned short*)(ws + 41287680);      // [40][64][2048] bf16
  float2* cstab       = (float2*)(ws + 51773440);              // 2048x32 float2
  hipLaunchKernelGGL(prep_kernel, dim3(7616), dim3(256), 0, stream, X, Wq, Wk, Wv, Xb, WT, cstab);
  hipLaunchKernelGGL(qkv_gemm_kernel, dim3(960), dim3(256), 0, stream, Xb, WT, bq, bk, bv, cstab, Qr, Kr, VTt);
  hipLaunchKernelGGL(attn_kernel, dim3(1280), dim3(256), 0, stream, Qr, Kr, VTt, (float*)d_out);
}

// Round 8
// 242.819 us; speedup vs baseline: 1.8027x; 1.1449x over previous
//
#include <hip/hip_runtime.h>

#define DD 1280
#define SS 2048
#define HH 20

typedef __bf16 bf16x8 __attribute__((ext_vector_type(8)));
typedef float f32x4 __attribute__((ext_vector_type(4)));

typedef __attribute__((address_space(3))) unsigned int lds_uint;
typedef __attribute__((address_space(1))) unsigned int glb_uint;
#define GLL16(g, l) __builtin_amdgcn_global_load_lds((const glb_uint*)(g), (lds_uint*)(l), 16, 0, 0)

__device__ __forceinline__ unsigned short f2bf(float f) {
  union { float f; unsigned u; } v; v.f = f;
  unsigned r = v.u + 0x7fffu + ((v.u >> 16) & 1u);
  return (unsigned short)(r >> 16);
}
__device__ __forceinline__ unsigned f2u(float f) {
  union { float f; unsigned u; } v; v.f = f; return v.u;
}

// ---- prep: cast X to bf16; transpose-cast W -> WT[n][k]; rotary cos/sin table ----
__global__ __launch_bounds__(256) void prep_kernel(
    const float* __restrict__ X, const float* __restrict__ Wq,
    const float* __restrict__ Wk, const float* __restrict__ Wv,
    unsigned short* __restrict__ Xb, unsigned short* __restrict__ WT,
    float2* __restrict__ cs) {
  __shared__ unsigned short tile[32][33];
  int bid = blockIdx.x, tid = threadIdx.x;
  if (bid < 2560) {
    size_t base = (size_t)bid * 2048 + (size_t)tid * 8;
    const float4* xin = (const float4*)(X + base);
    float4 a = xin[0], c = xin[1];
    ushort4 o0 = make_ushort4(f2bf(a.x), f2bf(a.y), f2bf(a.z), f2bf(a.w));
    ushort4 o1 = make_ushort4(f2bf(c.x), f2bf(c.y), f2bf(c.z), f2bf(c.w));
    *(ushort4*)(Xb + base) = o0;
    *(ushort4*)(Xb + base + 4) = o1;
  } else if (bid < 7360) {
    int wb = bid - 2560;          // 3 * 1600 tiles of 32x32
    int mat = wb / 1600;
    int t = wb % 1600;
    int tn = t % 40, tk = t / 40;
    const float* W = (mat == 0) ? Wq : ((mat == 1) ? Wk : Wv);
    int k0 = tk * 32, n0 = tn * 32;
    int tc = tid & 31, tr = tid >> 5;
#pragma unroll
    for (int i = 0; i < 4; i++) {
      int kl = tr + i * 8;
      tile[kl][tc] = f2bf(W[(size_t)(k0 + kl) * DD + n0 + tc]);
    }
    __syncthreads();
    unsigned short* out = WT + (size_t)mat * DD * DD;
#pragma unroll
    for (int i = 0; i < 4; i++) {
      int nl = tr + i * 8;
      out[(size_t)(n0 + nl) * DD + k0 + tc] = tile[tc][nl];
    }
  } else {
    // rotary table: cs[sp][j] = (cos, sin)(sp * 10000^(-j/32)), 2048 x 32
    int idx = (bid - 7360) * 256 + tid;     // 256 blocks -> 65536 entries
    int sp = idx >> 5, j = idx & 31;
    float invf = exp2f(-(float)j * 0.41524101186092034f);
    float ang = (float)sp * invf;
    cs[idx] = make_float2(cosf(ang), sinf(ang));
  }
}

// ---- QKV GEMM: round-0 m97/BK=32 structure RESTORED verbatim (proven <=96us)
// + T1 XCD-chunked blockIdx swizzle (960%8==0 -> simple bijective remap).
// r7 postmortem: BK=64 regressed (104us, Occupancy 10%): 32KB LDS + 144 VGPR
// cut blocks/CU, losing the cross-block overlap that hides the vmcnt(0)
// drain (m132's lesson at smaller scale).  FETCH_SIZE 168MB ~= 4x inputs ->
// default round-robin XCD placement scatters panel-sharing blocks across
// non-coherent L2s; chunked swizzle makes panel reuse L2-local.
__global__ __launch_bounds__(256) void qkv_gemm_kernel(
    const unsigned short* __restrict__ Xb, const unsigned short* __restrict__ WT,
    const float* __restrict__ bq, const float* __restrict__ bk, const float* __restrict__ bv,
    const float2* __restrict__ cs,
    unsigned short* __restrict__ Qr, unsigned short* __restrict__ Kr,
    unsigned short* __restrict__ VT) {
  __shared__ __align__(16) unsigned short As[128 * 32];
  __shared__ __align__(16) unsigned short Bs[128 * 32];
  int bx0 = blockIdx.x;           // 960 = 8 XCDs * 120
  int bx = (bx0 & 7) * 120 + (bx0 >> 3);   // XCD c works contiguous [c*120, c*120+120)
  int mat = bx / 320;
  int r0 = bx % 320;
  int tm = r0 / 10, tn = r0 % 10;
  int m0 = tm * 128, n0 = tn * 128;
  int tid = threadIdx.x;
  int lane = tid & 63, wave = tid >> 6;
  int c15 = lane & 15, quad = lane >> 4;
  int wm = wave >> 1, wn = wave & 1;
  const unsigned short* Wm = WT + (size_t)mat * DD * DD;

  int rowA = tid >> 2;
  int c8 = (tid & 3) * 8;
  const unsigned short* gA0 = Xb + (size_t)(m0 + rowA) * DD + c8;
  const unsigned short* gA1 = gA0 + (size_t)64 * DD;
  const unsigned short* gB0 = Wm + (size_t)(n0 + rowA) * DD + c8;
  const unsigned short* gB1 = gB0 + (size_t)64 * DD;
  unsigned short* ldsA0 = As + wave * 512;          // rows 0..63
  unsigned short* ldsA1 = As + 2048 + wave * 512;   // rows 64..127
  unsigned short* ldsB0 = Bs + wave * 512;
  unsigned short* ldsB1 = Bs + 2048 + wave * 512;

  f32x4 acc[4][4] = {};

  for (int kk = 0; kk < DD; kk += 32) {
    __syncthreads();
    GLL16(gA0 + kk, ldsA0);
    GLL16(gA1 + kk, ldsA1);
    GLL16(gB0 + kk, ldsB0);
    GLL16(gB1 + kk, ldsB1);
    __syncthreads();
    bf16x8 af[4];
#pragma unroll
    for (int mi = 0; mi < 4; mi++)
      af[mi] = *(const bf16x8*)(As + (wm * 64 + mi * 16 + c15) * 32 + quad * 8);
#pragma unroll
    for (int ni = 0; ni < 4; ni++) {
      bf16x8 bfr = *(const bf16x8*)(Bs + (wn * 64 + ni * 16 + c15) * 32 + quad * 8);
#pragma unroll
      for (int mi = 0; mi < 4; mi++)
        acc[mi][ni] = __builtin_amdgcn_mfma_f32_16x16x32_bf16(af[mi], bfr, acc[mi][ni], 0, 0, 0);
    }
  }

  int growb = m0 + wm * 64;
  int gcolb = n0 + wn * 64;
  if (mat == 2) {
    // V: write transposed VT[(b*H+h)*64+d][s]
#pragma unroll
    for (int mi = 0; mi < 4; mi++) {
      int row0 = growb + mi * 16 + quad * 4;
      int bb_ = row0 >> 11, sp = row0 & 2047;
#pragma unroll
      for (int ni = 0; ni < 4; ni++) {
        int gcol = gcolb + ni * 16 + c15;
        float bias = bv[gcol];
        int hh = gcol >> 6, dd = gcol & 63;
        f32x4 v = acc[mi][ni];
        ushort4 o = make_ushort4(f2bf(v[0] + bias), f2bf(v[1] + bias),
                                 f2bf(v[2] + bias), f2bf(v[3] + bias));
        *(ushort4*)(VT + ((size_t)((bb_ * HH + hh) * 64 + dd)) * SS + sp) = o;
      }
    }
  } else {
    // Q / K: bias + rotary via cs table; each wave's 64 cols = exactly one head,
    // rotary pair (d, d+32) = acc frags (ni, ni+2), same lane.
    unsigned short* Out = (mat == 0) ? Qr : Kr;
    const float* bias = (mat == 0) ? bq : bk;
    float qs = (mat == 0) ? 0.18033688011112042f : 1.0f;  // 0.125*log2(e) for Q
#pragma unroll
    for (int mi = 0; mi < 4; mi++) {
      int row0 = growb + mi * 16 + quad * 4;
#pragma unroll
      for (int ni = 0; ni < 2; ni++) {
        int gcol_lo = gcolb + ni * 16 + c15;      // d in [0,32) within head
        int gcol_hi = gcol_lo + 32;
        float blo = bias[gcol_lo], bhi = bias[gcol_hi];
        int d = ni * 16 + c15;
        f32x4 lo = acc[mi][ni], hi = acc[mi][ni + 2];
#pragma unroll
        for (int r = 0; r < 4; r++) {
          int grow = row0 + r;
          float2 cv = cs[(size_t)(grow & 2047) * 32 + d];
          float xl = (lo[r] + blo) * qs, xh = (hi[r] + bhi) * qs;
          Out[(size_t)grow * DD + gcol_lo] = f2bf(xl * cv.x - xh * cv.y);
          Out[(size_t)grow * DD + gcol_hi] = f2bf(xh * cv.x + xl * cv.y);
        }
      }
    }
  }
}

// ---- flash attention v13: v6 structure (proven) + T5 s_setprio around MFMA ----
__device__ __forceinline__ void attn_load_frags(
    bf16x8 (&kf)[2][2], bf16x8 (&vf)[4],
    const unsigned short* Kt, const unsigned short* Vt, int c15, int quad) {
#pragma unroll
  for (int ni = 0; ni < 2; ni++)
#pragma unroll
    for (int kc = 0; kc < 2; kc++)
      kf[ni][kc] = *(const bf16x8*)(Kt + (size_t)(ni * 16 + c15) * DD + kc * 32 + quad * 8);
#pragma unroll
  for (int nio = 0; nio < 4; nio++)
    vf[nio] = *(const bf16x8*)(Vt + (size_t)(nio * 16 + c15) * SS + quad * 8);
}

__device__ __forceinline__ void attn_tile(
    const bf16x8 (&qf)[4][2], const bf16x8 (&kf)[2][2], const bf16x8 (&vf)[4],
    const bf16x8& ones, f32x4 (&of)[4][4], f32x4 (&ol)[4],
    unsigned short* Pw, int c15, int quad) {
  // S = Q K^T  (64q x 32k per wave)
  f32x4 sc[4][2] = {};
  __builtin_amdgcn_s_setprio(1);
#pragma unroll
  for (int ni = 0; ni < 2; ni++)
#pragma unroll
    for (int kc = 0; kc < 2; kc++)
#pragma unroll
      for (int mi = 0; mi < 4; mi++)
        sc[mi][ni] = __builtin_amdgcn_mfma_f32_16x16x32_bf16(qf[mi][kc], kf[ni][kc], sc[mi][ni], 0, 0, 0);
  __builtin_amdgcn_s_setprio(0);

  int pos_r = (quad + 2 * ((c15 >> 2) & 3) + (c15 & 3)) & 7;   // read-side swizzle

#define PROD(mi)                                                              \
  {                                                                           \
    _Pragma("unroll")                                                         \
    for (int ni = 0; ni < 2; ni++) {                                          \
      int kc8 = ni * 2 + (c15 >> 3);                                          \
      _Pragma("unroll")                                                       \
      for (int r = 0; r < 4; r++) {                                           \
        unsigned u = f2u(__builtin_amdgcn_exp2f(sc[mi][ni][r]));              \
        int q = (mi) * 16 + quad * 4 + r;                                     \
        int pos = (kc8 + 2 * quad + r) & 7;                                   \
        Pw[q * 64 + pos * 8 + (c15 & 7)] = (unsigned short)(u >> 16);         \
      }                                                                       \
    }                                                                         \
  }
#define CONS(mi)                                                              \
  {                                                                           \
    bf16x8 pf = *(const bf16x8*)(Pw + ((mi) * 16 + c15) * 64 + pos_r * 8);    \
    __builtin_amdgcn_s_setprio(1);                                            \
    _Pragma("unroll")                                                         \
    for (int nio = 0; nio < 4; nio++)                                         \
      of[mi][nio] = __builtin_amdgcn_mfma_f32_16x16x32_bf16(pf, vf[nio],      \
                                                            of[mi][nio], 0, 0, 0); \
    ol[mi] = __builtin_amdgcn_mfma_f32_16x16x32_bf16(pf, ones, ol[mi], 0, 0, 0); \
    __builtin_amdgcn_s_setprio(0);                                            \
  }

  PROD(0);
  PROD(1); CONS(0);
  PROD(2); CONS(1);
  PROD(3); CONS(2);
  CONS(3);
#undef PROD
#undef CONS
}

__global__ __launch_bounds__(256)
__attribute__((amdgpu_waves_per_eu(2, 4)))
void attn_kernel(
    const unsigned short* __restrict__ Qr, const unsigned short* __restrict__ Kr,
    const unsigned short* __restrict__ VT, float* __restrict__ out) {
  __shared__ __align__(16) unsigned short Pall[4 * 64 * 64];  // 32 KB: per-wave P strips
  __shared__ float Lbuf[64];
  int bx = blockIdx.x;             // bx = qt*40 + bh; head pinned to one XCD (40%8==0)
  int bh = bx % 40, qt = bx / 40;
  int b = bh / HH, h = bh % HH;
  int tid = threadIdx.x;
  int lane = tid & 63, w = tid >> 6;
  int c15 = lane & 15, quad = lane >> 4;
  int q0 = qt * 64;

  // Q frags direct from global (A-layout: lane m=c15, k=quad*8), kept in regs
  const unsigned short* Qbase = Qr + (size_t)(b * SS + q0) * DD + h * 64;
  bf16x8 qf[4][2];
#pragma unroll
  for (int mi = 0; mi < 4; mi++)
#pragma unroll
    for (int kc = 0; kc < 2; kc++)
      qf[mi][kc] = *(const bf16x8*)(Qbase + (size_t)(mi * 16 + c15) * DD + kc * 32 + quad * 8);

  const unsigned short* Kbase = Kr + (size_t)(b * SS + w * 32) * DD + h * 64;
  const unsigned short* Vbase = VT + (size_t)(bh * 64) * SS + w * 32;
  unsigned short* Pw = Pall + w * 4096;   // 64 rows x 64 shorts

  bf16x8 ones;
#pragma unroll
  for (int i = 0; i < 8; i++) ones[i] = (__bf16)1.0f;

  f32x4 of[4][4] = {};       // [mi][nio]
  f32x4 ol[4] = {};          // l via P*ones

  bf16x8 kfb[2][2][2], vfb[2][4];   // double-buffered K/V fragments
  attn_load_frags(kfb[0], vfb[0], Kbase, Vbase, c15, quad);

  for (int t = 0; t < 16; t += 2) {
    // issue t+1 loads into buf1 before computing buf0
    attn_load_frags(kfb[1], vfb[1],
                    Kbase + (size_t)((t + 1) * 128) * DD, Vbase + (t + 1) * 128,
                    c15, quad);
    attn_tile(qf, kfb[0], vfb[0], ones, of, ol, Pw, c15, quad);
    if (t + 2 < 16)
      attn_load_frags(kfb[0], vfb[0],
                      Kbase + (size_t)((t + 2) * 128) * DD, Vbase + (t + 2) * 128,
                      c15, quad);
    attn_tile(qf, kfb[1], vfb[1], ones, of, ol, Pw, c15, quad);
  }

  // all waves done with their P strips -> safe to overlay Obuf on Pall
  __syncthreads();
  float* Obuf = (float*)Pall;      // 64 x 65 floats = 16.6 KB of the 32 KB strip area

  // cross-wave reduction of O and l (serialized passes)
  for (int pass = 0; pass < 4; pass++) {
    if (w == pass) {
#pragma unroll
      for (int mi = 0; mi < 4; mi++)
#pragma unroll
        for (int nio = 0; nio < 4; nio++)
#pragma unroll
          for (int r = 0; r < 4; r++) {
            int q = mi * 16 + quad * 4 + r;
            int d = nio * 16 + c15;
            if (pass == 0) Obuf[q * 65 + d] = of[mi][nio][r];
            else           Obuf[q * 65 + d] += of[mi][nio][r];
          }
      if (c15 == 0) {
#pragma unroll
        for (int mi = 0; mi < 4; mi++)
#pragma unroll
          for (int r = 0; r < 4; r++) {
            int q = mi * 16 + quad * 4 + r;
            if (pass == 0) Lbuf[q] = ol[mi][r];
            else           Lbuf[q] += ol[mi][r];
          }
      }
    }
    __syncthreads();
  }

  // epilogue: each wave writes 16 q-rows; lane covers 16 consecutive d
  {
    int row = w * 16 + (lane >> 2);
    int col0 = (lane & 3) * 16;
    float invl = 1.0f / Lbuf[row];
    float* op = out + (size_t)(b * SS + q0 + row) * DD + h * 64 + col0;
    const float* ob = Obuf + row * 65 + col0;
#pragma unroll
    for (int j = 0; j < 4; j++) {
      float4 v = make_float4(ob[j * 4 + 0] * invl, ob[j * 4 + 1] * invl,
                             ob[j * 4 + 2] * invl, ob[j * 4 + 3] * invl);
      *(float4*)(op + j * 4) = v;
    }
  }
}

extern "C" void kernel_launch(void* const* d_in, const int* in_sizes, int n_in,
                              void* d_out, int out_size, void* d_ws, size_t ws_size,
                              hipStream_t stream) {
  (void)in_sizes; (void)n_in; (void)out_size; (void)ws_size;
  const float* X  = (const float*)d_in[0];
  const float* Wq = (const float*)d_in[1];
  const float* bq = (const float*)d_in[2];
  const float* Wk = (const float*)d_in[3];
  const float* bk = (const float*)d_in[4];
  const float* Wv = (const float*)d_in[5];
  const float* bv = (const float*)d_in[6];
  char* ws = (char*)d_ws;
  unsigned short* Xb  = (unsigned short*)(ws);                 // 4096x1280 bf16
  unsigned short* WT  = (unsigned short*)(ws + 10485760);      // 3x1280x1280 bf16 (transposed)
  unsigned short* Qr  = (unsigned short*)(ws + 20316160);      // 4096x1280 bf16 (rotary'd, scaled)
  unsigned short* Kr  = (unsigned short*)(ws + 30801920);      // 4096x1280 bf16 (rotary'd)
  unsigned short* VTt = (unsigned short*)(ws + 41287680);      // [40][64][2048] bf16
  float2* cstab       = (float2*)(ws + 51773440);              // 2048x32 float2
  hipLaunchKernelGGL(prep_kernel, dim3(7616), dim3(256), 0, stream, X, Wq, Wk, Wv, Xb, WT, cstab);
  hipLaunchKernelGGL(qkv_gemm_kernel, dim3(960), dim3(256), 0, stream, Xb, WT, bq, bk, bv, cstab, Qr, Kr, VTt);
  hipLaunchKernelGGL(attn_kernel, dim3(1280), dim3(256), 0, stream, Qr, Kr, VTt, (float*)d_out);
}

// Round 10
// 242.240 us; speedup vs baseline: 1.8070x; 1.0024x over previous
//
#include <hip/hip_runtime.h>

#define DD 1280
#define SS 2048
#define HH 20

typedef __bf16 bf16x8 __attribute__((ext_vector_type(8)));
typedef float f32x4 __attribute__((ext_vector_type(4)));

typedef __attribute__((address_space(3))) unsigned int lds_uint;
typedef __attribute__((address_space(1))) unsigned int glb_uint;
#define GLL16(g, l) __builtin_amdgcn_global_load_lds((const glb_uint*)(g), (lds_uint*)(l), 16, 0, 0)

__device__ __forceinline__ unsigned short f2bf(float f) {
  union { float f; unsigned u; } v; v.f = f;
  unsigned r = v.u + 0x7fffu + ((v.u >> 16) & 1u);
  return (unsigned short)(r >> 16);
}
__device__ __forceinline__ unsigned f2u(float f) {
  union { float f; unsigned u; } v; v.f = f; return v.u;
}
__device__ __forceinline__ unsigned pk2(float lo, float hi) {
  return ((unsigned)f2bf(hi) << 16) | (unsigned)f2bf(lo);
}

// ---- prep v2: fully vectorized (r8 postmortem: prep ~65-70us by subtraction,
// VMEM-instruction-issue-bound from scalar 4B loads / 2B stores in the W
// transpose ~ 13M global memory instrs).  SegA: 2x float4 load -> ONE 16B
// packed store.  SegB: float4 load -> LDS[32][36] (8B-aligned ushort4 vector
// writes) -> ushort4 transposed store (64B/row per 8 lanes).  ~4M instrs.
// (Resubmitted verbatim: r9 bench was an infra failure, not a kernel result.)
__global__ __launch_bounds__(256) void prep_kernel(
    const float* __restrict__ X, const float* __restrict__ Wq,
    const float* __restrict__ Wk, const float* __restrict__ Wv,
    unsigned short* __restrict__ Xb, unsigned short* __restrict__ WT,
    float2* __restrict__ cs) {
  __shared__ __align__(8) unsigned short tile[32][36];
  int bid = blockIdx.x, tid = threadIdx.x;
  if (bid < 2560) {
    size_t base = (size_t)bid * 2048 + (size_t)tid * 8;
    const float4* xin = (const float4*)(X + base);
    float4 a = xin[0], c = xin[1];
    uint4 o = make_uint4(pk2(a.x, a.y), pk2(a.z, a.w), pk2(c.x, c.y), pk2(c.z, c.w));
    *(uint4*)(Xb + base) = o;
  } else if (bid < 7360) {
    int wb = bid - 2560;          // 3 * 1600 tiles of 32x32
    int mat = wb / 1600;
    int t = wb % 1600;
    int tn = t % 40, tk = t / 40;
    const float* W = (mat == 0) ? Wq : ((mat == 1) ? Wk : Wv);
    int k0 = tk * 32, n0 = tn * 32;
    int r = tid >> 3, cq = tid & 7;   // 256 threads = 32 rows x 8 col-quads
    float4 wv = *(const float4*)(W + (size_t)(k0 + r) * DD + n0 + cq * 4);
    *(ushort4*)&tile[r][cq * 4] =
        make_ushort4(f2bf(wv.x), f2bf(wv.y), f2bf(wv.z), f2bf(wv.w));
    __syncthreads();
    unsigned short* out = WT + (size_t)mat * DD * DD;
    // transposed: row n = r, k-quad = cq
    ushort4 o = make_ushort4(tile[cq * 4 + 0][r], tile[cq * 4 + 1][r],
                             tile[cq * 4 + 2][r], tile[cq * 4 + 3][r]);
    *(ushort4*)(out + (size_t)(n0 + r) * DD + k0 + cq * 4) = o;
  } else {
    // rotary table: cs[sp][j] = (cos, sin)(sp * 10000^(-j/32)), 2048 x 32
    int idx = (bid - 7360) * 256 + tid;     // 256 blocks -> 65536 entries
    int sp = idx >> 5, j = idx & 31;
    float invf = exp2f(-(float)j * 0.41524101186092034f);
    float ang = (float)sp * invf;
    cs[idx] = make_float2(cosf(ang), sinf(ang));
  }
}

// ---- QKV GEMM: m97/BK=32 structure + T1 XCD-chunked swizzle (r8: proven, ~68us) ----
__global__ __launch_bounds__(256) void qkv_gemm_kernel(
    const unsigned short* __restrict__ Xb, const unsigned short* __restrict__ WT,
    const float* __restrict__ bq, const float* __restrict__ bk, const float* __restrict__ bv,
    const float2* __restrict__ cs,
    unsigned short* __restrict__ Qr, unsigned short* __restrict__ Kr,
    unsigned short* __restrict__ VT) {
  __shared__ __align__(16) unsigned short As[128 * 32];
  __shared__ __align__(16) unsigned short Bs[128 * 32];
  int bx0 = blockIdx.x;           // 960 = 8 XCDs * 120
  int bx = (bx0 & 7) * 120 + (bx0 >> 3);   // XCD c works contiguous [c*120, c*120+120)
  int mat = bx / 320;
  int r0 = bx % 320;
  int tm = r0 / 10, tn = r0 % 10;
  int m0 = tm * 128, n0 = tn * 128;
  int tid = threadIdx.x;
  int lane = tid & 63, wave = tid >> 6;
  int c15 = lane & 15, quad = lane >> 4;
  int wm = wave >> 1, wn = wave & 1;
  const unsigned short* Wm = WT + (size_t)mat * DD * DD;

  int rowA = tid >> 2;
  int c8 = (tid & 3) * 8;
  const unsigned short* gA0 = Xb + (size_t)(m0 + rowA) * DD + c8;
  const unsigned short* gA1 = gA0 + (size_t)64 * DD;
  const unsigned short* gB0 = Wm + (size_t)(n0 + rowA) * DD + c8;
  const unsigned short* gB1 = gB0 + (size_t)64 * DD;
  unsigned short* ldsA0 = As + wave * 512;          // rows 0..63
  unsigned short* ldsA1 = As + 2048 + wave * 512;   // rows 64..127
  unsigned short* ldsB0 = Bs + wave * 512;
  unsigned short* ldsB1 = Bs + 2048 + wave * 512;

  f32x4 acc[4][4] = {};

  for (int kk = 0; kk < DD; kk += 32) {
    __syncthreads();
    GLL16(gA0 + kk, ldsA0);
    GLL16(gA1 + kk, ldsA1);
    GLL16(gB0 + kk, ldsB0);
    GLL16(gB1 + kk, ldsB1);
    __syncthreads();
    bf16x8 af[4];
#pragma unroll
    for (int mi = 0; mi < 4; mi++)
      af[mi] = *(const bf16x8*)(As + (wm * 64 + mi * 16 + c15) * 32 + quad * 8);
#pragma unroll
    for (int ni = 0; ni < 4; ni++) {
      bf16x8 bfr = *(const bf16x8*)(Bs + (wn * 64 + ni * 16 + c15) * 32 + quad * 8);
#pragma unroll
      for (int mi = 0; mi < 4; mi++)
        acc[mi][ni] = __builtin_amdgcn_mfma_f32_16x16x32_bf16(af[mi], bfr, acc[mi][ni], 0, 0, 0);
    }
  }

  int growb = m0 + wm * 64;
  int gcolb = n0 + wn * 64;
  if (mat == 2) {
    // V: write transposed VT[(b*H+h)*64+d][s]
#pragma unroll
    for (int mi = 0; mi < 4; mi++) {
      int row0 = growb + mi * 16 + quad * 4;
      int bb_ = row0 >> 11, sp = row0 & 2047;
#pragma unroll
      for (int ni = 0; ni < 4; ni++) {
        int gcol = gcolb + ni * 16 + c15;
        float bias = bv[gcol];
        int hh = gcol >> 6, dd = gcol & 63;
        f32x4 v = acc[mi][ni];
        ushort4 o = make_ushort4(f2bf(v[0] + bias), f2bf(v[1] + bias),
                                 f2bf(v[2] + bias), f2bf(v[3] + bias));
        *(ushort4*)(VT + ((size_t)((bb_ * HH + hh) * 64 + dd)) * SS + sp) = o;
      }
    }
  } else {
    // Q / K: bias + rotary via cs table; each wave's 64 cols = exactly one head,
    // rotary pair (d, d+32) = acc frags (ni, ni+2), same lane.
    unsigned short* Out = (mat == 0) ? Qr : Kr;
    const float* bias = (mat == 0) ? bq : bk;
    float qs = (mat == 0) ? 0.18033688011112042f : 1.0f;  // 0.125*log2(e) for Q
#pragma unroll
    for (int mi = 0; mi < 4; mi++) {
      int row0 = growb + mi * 16 + quad * 4;
#pragma unroll
      for (int ni = 0; ni < 2; ni++) {
        int gcol_lo = gcolb + ni * 16 + c15;      // d in [0,32) within head
        int gcol_hi = gcol_lo + 32;
        float blo = bias[gcol_lo], bhi = bias[gcol_hi];
        int d = ni * 16 + c15;
        f32x4 lo = acc[mi][ni], hi = acc[mi][ni + 2];
#pragma unroll
        for (int r = 0; r < 4; r++) {
          int grow = row0 + r;
          float2 cv = cs[(size_t)(grow & 2047) * 32 + d];
          float xl = (lo[r] + blo) * qs, xh = (hi[r] + bhi) * qs;
          Out[(size_t)grow * DD + gcol_lo] = f2bf(xl * cv.x - xh * cv.y);
          Out[(size_t)grow * DD + gcol_hi] = f2bf(xh * cv.x + xl * cv.y);
        }
      }
    }
  }
}

// ---- flash attention: v6 EXACT (96.5us proven; r8 A/B showed setprio -8% -> removed) ----
__device__ __forceinline__ void attn_load_frags(
    bf16x8 (&kf)[2][2], bf16x8 (&vf)[4],
    const unsigned short* Kt, const unsigned short* Vt, int c15, int quad) {
#pragma unroll
  for (int ni = 0; ni < 2; ni++)
#pragma unroll
    for (int kc = 0; kc < 2; kc++)
      kf[ni][kc] = *(const bf16x8*)(Kt + (size_t)(ni * 16 + c15) * DD + kc * 32 + quad * 8);
#pragma unroll
  for (int nio = 0; nio < 4; nio++)
    vf[nio] = *(const bf16x8*)(Vt + (size_t)(nio * 16 + c15) * SS + quad * 8);
}

__device__ __forceinline__ void attn_tile(
    const bf16x8 (&qf)[4][2], const bf16x8 (&kf)[2][2], const bf16x8 (&vf)[4],
    const bf16x8& ones, f32x4 (&of)[4][4], f32x4 (&ol)[4],
    unsigned short* Pw, int c15, int quad) {
  // S = Q K^T  (64q x 32k per wave)
  f32x4 sc[4][2] = {};
#pragma unroll
  for (int ni = 0; ni < 2; ni++)
#pragma unroll
    for (int kc = 0; kc < 2; kc++)
#pragma unroll
      for (int mi = 0; mi < 4; mi++)
        sc[mi][ni] = __builtin_amdgcn_mfma_f32_16x16x32_bf16(qf[mi][kc], kf[ni][kc], sc[mi][ni], 0, 0, 0);

  int pos_r = (quad + 2 * ((c15 >> 2) & 3) + (c15 & 3)) & 7;   // read-side swizzle

#define PROD(mi)                                                              \
  {                                                                           \
    _Pragma("unroll")                                                         \
    for (int ni = 0; ni < 2; ni++) {                                          \
      int kc8 = ni * 2 + (c15 >> 3);                                          \
      _Pragma("unroll")                                                       \
      for (int r = 0; r < 4; r++) {                                           \
        unsigned u = f2u(__builtin_amdgcn_exp2f(sc[mi][ni][r]));              \
        int q = (mi) * 16 + quad * 4 + r;                                     \
        int pos = (kc8 + 2 * quad + r) & 7;                                   \
        Pw[q * 64 + pos * 8 + (c15 & 7)] = (unsigned short)(u >> 16);         \
      }                                                                       \
    }                                                                         \
  }
#define CONS(mi)                                                              \
  {                                                                           \
    bf16x8 pf = *(const bf16x8*)(Pw + ((mi) * 16 + c15) * 64 + pos_r * 8);    \
    _Pragma("unroll")                                                         \
    for (int nio = 0; nio < 4; nio++)                                         \
      of[mi][nio] = __builtin_amdgcn_mfma_f32_16x16x32_bf16(pf, vf[nio],      \
                                                            of[mi][nio], 0, 0, 0); \
    ol[mi] = __builtin_amdgcn_mfma_f32_16x16x32_bf16(pf, ones, ol[mi], 0, 0, 0); \
  }

  PROD(0);
  PROD(1); CONS(0);
  PROD(2); CONS(1);
  PROD(3); CONS(2);
  CONS(3);
#undef PROD
#undef CONS
}

__global__ __launch_bounds__(256)
__attribute__((amdgpu_waves_per_eu(2, 4)))
void attn_kernel(
    const unsigned short* __restrict__ Qr, const unsigned short* __restrict__ Kr,
    const unsigned short* __restrict__ VT, float* __restrict__ out) {
  __shared__ __align__(16) unsigned short Pall[4 * 64 * 64];  // 32 KB: per-wave P strips
  __shared__ float Lbuf[64];
  int bx = blockIdx.x;             // bx = qt*40 + bh; head pinned to one XCD (40%8==0)
  int bh = bx % 40, qt = bx / 40;
  int b = bh / HH, h = bh % HH;
  int tid = threadIdx.x;
  int lane = tid & 63, w = tid >> 6;
  int c15 = lane & 15, quad = lane >> 4;
  int q0 = qt * 64;

  // Q frags direct from global (A-layout: lane m=c15, k=quad*8), kept in regs
  const unsigned short* Qbase = Qr + (size_t)(b * SS + q0) * DD + h * 64;
  bf16x8 qf[4][2];
#pragma unroll
  for (int mi = 0; mi < 4; mi++)
#pragma unroll
    for (int kc = 0; kc < 2; kc++)
      qf[mi][kc] = *(const bf16x8*)(Qbase + (size_t)(mi * 16 + c15) * DD + kc * 32 + quad * 8);

  const unsigned short* Kbase = Kr + (size_t)(b * SS + w * 32) * DD + h * 64;
  const unsigned short* Vbase = VT + (size_t)(bh * 64) * SS + w * 32;
  unsigned short* Pw = Pall + w * 4096;   // 64 rows x 64 shorts

  bf16x8 ones;
#pragma unroll
  for (int i = 0; i < 8; i++) ones[i] = (__bf16)1.0f;

  f32x4 of[4][4] = {};       // [mi][nio]
  f32x4 ol[4] = {};          // l via P*ones

  bf16x8 kfb[2][2][2], vfb[2][4];   // double-buffered K/V fragments
  attn_load_frags(kfb[0], vfb[0], Kbase, Vbase, c15, quad);

  for (int t = 0; t < 16; t += 2) {
    // issue t+1 loads into buf1 before computing buf0
    attn_load_frags(kfb[1], vfb[1],
                    Kbase + (size_t)((t + 1) * 128) * DD, Vbase + (t + 1) * 128,
                    c15, quad);
    attn_tile(qf, kfb[0], vfb[0], ones, of, ol, Pw, c15, quad);
    if (t + 2 < 16)
      attn_load_frags(kfb[0], vfb[0],
                      Kbase + (size_t)((t + 2) * 128) * DD, Vbase + (t + 2) * 128,
                      c15, quad);
    attn_tile(qf, kfb[1], vfb[1], ones, of, ol, Pw, c15, quad);
  }

  // all waves done with their P strips -> safe to overlay Obuf on Pall
  __syncthreads();
  float* Obuf = (float*)Pall;      // 64 x 65 floats = 16.6 KB of the 32 KB strip area

  // cross-wave reduction of O and l (serialized passes)
  for (int pass = 0; pass < 4; pass++) {
    if (w == pass) {
#pragma unroll
      for (int mi = 0; mi < 4; mi++)
#pragma unroll
        for (int nio = 0; nio < 4; nio++)
#pragma unroll
          for (int r = 0; r < 4; r++) {
            int q = mi * 16 + quad * 4 + r;
            int d = nio * 16 + c15;
            if (pass == 0) Obuf[q * 65 + d] = of[mi][nio][r];
            else           Obuf[q * 65 + d] += of[mi][nio][r];
          }
      if (c15 == 0) {
#pragma unroll
        for (int mi = 0; mi < 4; mi++)
#pragma unroll
          for (int r = 0; r < 4; r++) {
            int q = mi * 16 + quad * 4 + r;
            if (pass == 0) Lbuf[q] = ol[mi][r];
            else           Lbuf[q] += ol[mi][r];
          }
      }
    }
    __syncthreads();
  }

  // epilogue: each wave writes 16 q-rows; lane covers 16 consecutive d
  {
    int row = w * 16 + (lane >> 2);
    int col0 = (lane & 3) * 16;
    float invl = 1.0f / Lbuf[row];
    float* op = out + (size_t)(b * SS + q0 + row) * DD + h * 64 + col0;
    const float* ob = Obuf + row * 65 + col0;
#pragma unroll
    for (int j = 0; j < 4; j++) {
      float4 v = make_float4(ob[j * 4 + 0] * invl, ob[j * 4 + 1] * invl,
                             ob[j * 4 + 2] * invl, ob[j * 4 + 3] * invl);
      *(float4*)(op + j * 4) = v;
    }
  }
}

extern "C" void kernel_launch(void* const* d_in, const int* in_sizes, int n_in,
                              void* d_out, int out_size, void* d_ws, size_t ws_size,
                              hipStream_t stream) {
  (void)in_sizes; (void)n_in; (void)out_size; (void)ws_size;
  const float* X  = (const float*)d_in[0];
  const float* Wq = (const float*)d_in[1];
  const float* bq = (const float*)d_in[2];
  const float* Wk = (const float*)d_in[3];
  const float* bk = (const float*)d_in[4];
  const float* Wv = (const float*)d_in[5];
  const float* bv = (const float*)d_in[6];
  char* ws = (char*)d_ws;
  unsigned short* Xb  = (unsigned short*)(ws);                 // 4096x1280 bf16
  unsigned short* WT  = (unsigned short*)(ws + 10485760);      // 3x1280x1280 bf16 (transposed)
  unsigned short* Qr  = (unsigned short*)(ws + 20316160);      // 4096x1280 bf16 (rotary'd, scaled)
  unsigned short* Kr  = (unsigned short*)(ws + 30801920);      // 4096x1280 bf16 (rotary'd)
  unsigned short* VTt = (unsigned short*)(ws + 41287680);      // [40][64][2048] bf16
  float2* cstab       = (float2*)(ws + 51773440);              // 2048x32 float2
  hipLaunchKernelGGL(prep_kernel, dim3(7616), dim3(256), 0, stream, X, Wq, Wk, Wv, Xb, WT, cstab);
  hipLaunchKernelGGL(qkv_gemm_kernel, dim3(960), dim3(256), 0, stream, Xb, WT, bq, bk, bv, cstab, Qr, Kr, VTt);
  hipLaunchKernelGGL(attn_kernel, dim3(1280), dim3(256), 0, stream, Qr, Kr, VTt, (float*)d_out);
}

// Round 11
// 234.032 us; speedup vs baseline: 1.8704x; 1.0351x over previous
//
#include <hip/hip_runtime.h>

#define DD 1280
#define SS 2048
#define HH 20

typedef __bf16 bf16x8 __attribute__((ext_vector_type(8)));
typedef float f32x4 __attribute__((ext_vector_type(4)));

typedef __attribute__((address_space(3))) unsigned int lds_uint;
typedef __attribute__((address_space(1))) unsigned int glb_uint;
#define GLL16(g, l) __builtin_amdgcn_global_load_lds((const glb_uint*)(g), (lds_uint*)(l), 16, 0, 0)

__device__ __forceinline__ unsigned short f2bf(float f) {
  union { float f; unsigned u; } v; v.f = f;
  unsigned r = v.u + 0x7fffu + ((v.u >> 16) & 1u);
  return (unsigned short)(r >> 16);
}
__device__ __forceinline__ unsigned f2u(float f) {
  union { float f; unsigned u; } v; v.f = f; return v.u;
}
__device__ __forceinline__ unsigned pk2(float lo, float hi) {
  return ((unsigned)f2bf(hi) << 16) | (unsigned)f2bf(lo);
}

// ---- prep v2: fully vectorized (kept from r10; passed) ----
__global__ __launch_bounds__(256) void prep_kernel(
    const float* __restrict__ X, const float* __restrict__ Wq,
    const float* __restrict__ Wk, const float* __restrict__ Wv,
    unsigned short* __restrict__ Xb, unsigned short* __restrict__ WT,
    float2* __restrict__ cs) {
  __shared__ __align__(8) unsigned short tile[32][36];
  int bid = blockIdx.x, tid = threadIdx.x;
  if (bid < 2560) {
    size_t base = (size_t)bid * 2048 + (size_t)tid * 8;
    const float4* xin = (const float4*)(X + base);
    float4 a = xin[0], c = xin[1];
    uint4 o = make_uint4(pk2(a.x, a.y), pk2(a.z, a.w), pk2(c.x, c.y), pk2(c.z, c.w));
    *(uint4*)(Xb + base) = o;
  } else if (bid < 7360) {
    int wb = bid - 2560;          // 3 * 1600 tiles of 32x32
    int mat = wb / 1600;
    int t = wb % 1600;
    int tn = t % 40, tk = t / 40;
    const float* W = (mat == 0) ? Wq : ((mat == 1) ? Wk : Wv);
    int k0 = tk * 32, n0 = tn * 32;
    int r = tid >> 3, cq = tid & 7;   // 256 threads = 32 rows x 8 col-quads
    float4 wv = *(const float4*)(W + (size_t)(k0 + r) * DD + n0 + cq * 4);
    *(ushort4*)&tile[r][cq * 4] =
        make_ushort4(f2bf(wv.x), f2bf(wv.y), f2bf(wv.z), f2bf(wv.w));
    __syncthreads();
    unsigned short* out = WT + (size_t)mat * DD * DD;
    ushort4 o = make_ushort4(tile[cq * 4 + 0][r], tile[cq * 4 + 1][r],
                             tile[cq * 4 + 2][r], tile[cq * 4 + 3][r]);
    *(ushort4*)(out + (size_t)(n0 + r) * DD + k0 + cq * 4) = o;
  } else {
    // rotary table: cs[sp][j] = (cos, sin)(sp * 10000^(-j/32)), 2048 x 32
    int idx = (bid - 7360) * 256 + tid;     // 256 blocks -> 65536 entries
    int sp = idx >> 5, j = idx & 31;
    float invf = exp2f(-(float)j * 0.41524101186092034f);
    float ang = (float)sp * invf;
    cs[idx] = make_float2(cosf(ang), sinf(ang));
  }
}

// ---- QKV GEMM: m97/BK=32 structure + T1 XCD-chunked swizzle (r8: proven) ----
__global__ __launch_bounds__(256) void qkv_gemm_kernel(
    const unsigned short* __restrict__ Xb, const unsigned short* __restrict__ WT,
    const float* __restrict__ bq, const float* __restrict__ bk, const float* __restrict__ bv,
    const float2* __restrict__ cs,
    unsigned short* __restrict__ Qr, unsigned short* __restrict__ Kr,
    unsigned short* __restrict__ VT) {
  __shared__ __align__(16) unsigned short As[128 * 32];
  __shared__ __align__(16) unsigned short Bs[128 * 32];
  int bx0 = blockIdx.x;           // 960 = 8 XCDs * 120
  int bx = (bx0 & 7) * 120 + (bx0 >> 3);   // XCD c works contiguous [c*120, c*120+120)
  int mat = bx / 320;
  int r0 = bx % 320;
  int tm = r0 / 10, tn = r0 % 10;
  int m0 = tm * 128, n0 = tn * 128;
  int tid = threadIdx.x;
  int lane = tid & 63, wave = tid >> 6;
  int c15 = lane & 15, quad = lane >> 4;
  int wm = wave >> 1, wn = wave & 1;
  const unsigned short* Wm = WT + (size_t)mat * DD * DD;

  int rowA = tid >> 2;
  int c8 = (tid & 3) * 8;
  const unsigned short* gA0 = Xb + (size_t)(m0 + rowA) * DD + c8;
  const unsigned short* gA1 = gA0 + (size_t)64 * DD;
  const unsigned short* gB0 = Wm + (size_t)(n0 + rowA) * DD + c8;
  const unsigned short* gB1 = gB0 + (size_t)64 * DD;
  unsigned short* ldsA0 = As + wave * 512;          // rows 0..63
  unsigned short* ldsA1 = As + 2048 + wave * 512;   // rows 64..127
  unsigned short* ldsB0 = Bs + wave * 512;
  unsigned short* ldsB1 = Bs + 2048 + wave * 512;

  f32x4 acc[4][4] = {};

  for (int kk = 0; kk < DD; kk += 32) {
    __syncthreads();
    GLL16(gA0 + kk, ldsA0);
    GLL16(gA1 + kk, ldsA1);
    GLL16(gB0 + kk, ldsB0);
    GLL16(gB1 + kk, ldsB1);
    __syncthreads();
    bf16x8 af[4];
#pragma unroll
    for (int mi = 0; mi < 4; mi++)
      af[mi] = *(const bf16x8*)(As + (wm * 64 + mi * 16 + c15) * 32 + quad * 8);
#pragma unroll
    for (int ni = 0; ni < 4; ni++) {
      bf16x8 bfr = *(const bf16x8*)(Bs + (wn * 64 + ni * 16 + c15) * 32 + quad * 8);
#pragma unroll
      for (int mi = 0; mi < 4; mi++)
        acc[mi][ni] = __builtin_amdgcn_mfma_f32_16x16x32_bf16(af[mi], bfr, acc[mi][ni], 0, 0, 0);
    }
  }

  int growb = m0 + wm * 64;
  int gcolb = n0 + wn * 64;
  if (mat == 2) {
    // V: write transposed VT[(b*H+h)*64+d][s]
#pragma unroll
    for (int mi = 0; mi < 4; mi++) {
      int row0 = growb + mi * 16 + quad * 4;
      int bb_ = row0 >> 11, sp = row0 & 2047;
#pragma unroll
      for (int ni = 0; ni < 4; ni++) {
        int gcol = gcolb + ni * 16 + c15;
        float bias = bv[gcol];
        int hh = gcol >> 6, dd = gcol & 63;
        f32x4 v = acc[mi][ni];
        ushort4 o = make_ushort4(f2bf(v[0] + bias), f2bf(v[1] + bias),
                                 f2bf(v[2] + bias), f2bf(v[3] + bias));
        *(ushort4*)(VT + ((size_t)((bb_ * HH + hh) * 64 + dd)) * SS + sp) = o;
      }
    }
  } else {
    // Q / K: bias + rotary via cs table
    unsigned short* Out = (mat == 0) ? Qr : Kr;
    const float* bias = (mat == 0) ? bq : bk;
    float qs = (mat == 0) ? 0.18033688011112042f : 1.0f;  // 0.125*log2(e) for Q
#pragma unroll
    for (int mi = 0; mi < 4; mi++) {
      int row0 = growb + mi * 16 + quad * 4;
#pragma unroll
      for (int ni = 0; ni < 2; ni++) {
        int gcol_lo = gcolb + ni * 16 + c15;      // d in [0,32) within head
        int gcol_hi = gcol_lo + 32;
        float blo = bias[gcol_lo], bhi = bias[gcol_hi];
        int d = ni * 16 + c15;
        f32x4 lo = acc[mi][ni], hi = acc[mi][ni + 2];
#pragma unroll
        for (int r = 0; r < 4; r++) {
          int grow = row0 + r;
          float2 cv = cs[(size_t)(grow & 2047) * 32 + d];
          float xl = (lo[r] + blo) * qs, xh = (hi[r] + bhi) * qs;
          Out[(size_t)grow * DD + gcol_lo] = f2bf(xl * cv.x - xh * cv.y);
          Out[(size_t)grow * DD + gcol_hi] = f2bf(xh * cv.x + xl * cv.y);
        }
      }
    }
  }
}

// ---- flash attention v14: q-split waves + LDS-shared K/V ----
// r10: v6 is latency-bound (MfmaUtil 19.8, VALU 17.8, HBM 5.7, occ ~2
// waves/SIMD).  v6's wall: k-split waves each hold the FULL 64q x 64d acc
// (80 regs) -> ~192 total.  v14 splits q instead: wave w owns q rows
// [w*16, w*16+16) over ALL keys -> acc 16+4 regs; K/V become block-shared,
// staged per 32-key tile into LDS via global_load_lds (m97 1-barrier dbuf).
// Per-wave regs ~100 -> 4-5 waves/SIMD; cross-wave O/l reduction GONE.
// All MFMA maps = v6-verified 16x16x32 (A m=c15/k=quad*8+j; B same; C/D
// row=quad*4+r col=c15).  LDS swizzles: write chunk^f(row) == read
// chunk^f(row); GLL16 linear dest + pre-swizzled GLOBAL source (rule #21,
// refcheck-proven pattern in r7's BK=64 kernel).
//   K_lds[32k][64d] 128B rows: f(row)=row&7     (reads -> 2-way, free)
//   V_lds[64d][32k]  64B rows: f(row)=(row>>1)&3 (2-way)
//   P_w  [16q][32k]  64B rows: f(row)=(row>>1)&3 (2-way read)
__global__ __launch_bounds__(256)
void attn_kernel(
    const unsigned short* __restrict__ Qr, const unsigned short* __restrict__ Kr,
    const unsigned short* __restrict__ VT, float* __restrict__ out) {
  __shared__ __align__(16) unsigned short Klds[2][2048];  // [buf][32k][64d]
  __shared__ __align__(16) unsigned short Vlds[2][2048];  // [buf][64d][32k]
  __shared__ __align__(16) unsigned short Pall[4][512];   // per-wave [16q][32k]
  int bx = blockIdx.x;             // bx = qt*40 + bh; head pinned to one XCD (40%8==0)
  int bh = bx % 40, qt = bx / 40;
  int b = bh / HH, h = bh % HH;
  int tid = threadIdx.x;
  int lane = tid & 63, w = tid >> 6;
  int c15 = lane & 15, quad = lane >> 4;
  int q0 = qt * 64 + w * 16;       // this wave's 16 q rows

  // Q fragments in registers (A-operand: m=c15, k=quad*8+j per 32-d chunk)
  const unsigned short* Qb = Qr + (size_t)(b * SS + q0 + c15) * DD + h * 64 + quad * 8;
  bf16x8 qf[2];
  qf[0] = *(const bf16x8*)(Qb);
  qf[1] = *(const bf16x8*)(Qb + 32);

  // staging sources (per-thread, inverse-swizzled global column)
  int krow = tid >> 3, kch = tid & 7;          // K: 32 rows x 8 chunks
  const unsigned short* Ksrc = Kr + (size_t)(b * SS + krow) * DD + h * 64
                               + ((kch ^ (krow & 7)) * 8);
  int vrow = tid >> 2, vch = tid & 3;          // V: 64 rows x 4 chunks
  const unsigned short* Vsrc = VT + (size_t)(bh * 64 + vrow) * SS
                               + ((vch ^ ((vrow >> 1) & 3)) * 8);
  unsigned short* Pw = &Pall[w][0];

  bf16x8 ones;
#pragma unroll
  for (int i = 0; i < 8; i++) ones[i] = (__bf16)1.0f;

  f32x4 of[4] = {};   // [nio]: O[q=quad*4+r][d=nio*16+c15]
  f32x4 ol = {};      // l[q=quad*4+r] via P*ones

  // prologue: stage tile 0 into buf 0
  GLL16(Ksrc, &Klds[0][0] + w * 512);
  GLL16(Vsrc, &Vlds[0][0] + w * 512);
  __syncthreads();

  for (int t = 0; t < 64; t++) {
    int buf = t & 1;
    if (t + 1 < 64) {   // prefetch next tile into the other buffer
      GLL16(Ksrc + (size_t)((t + 1) * 32) * DD, &Klds[buf ^ 1][0] + w * 512);
      GLL16(Vsrc + (t + 1) * 32, &Vlds[buf ^ 1][0] + w * 512);
    }
    const unsigned short* Kb = &Klds[buf][0];
    const unsigned short* Vb = &Vlds[buf][0];

    // QK^T: S[16q x 32k]
    f32x4 sc[2] = {};
#pragma unroll
    for (int kc = 0; kc < 2; kc++)
#pragma unroll
      for (int ni = 0; ni < 2; ni++) {
        int R = ni * 16 + c15;
        bf16x8 kf = *(const bf16x8*)(Kb + R * 64 + (((kc * 4 + quad) ^ (R & 7)) * 8));
        sc[ni] = __builtin_amdgcn_mfma_f32_16x16x32_bf16(qf[kc], kf, sc[ni], 0, 0, 0);
      }

    // exp2 + pack into this wave's P strip (swizzled)
#pragma unroll
    for (int ni = 0; ni < 2; ni++)
#pragma unroll
      for (int r = 0; r < 4; r++) {
        unsigned u = f2u(__builtin_amdgcn_exp2f(sc[ni][r]));
        int q = quad * 4 + r;
        int sw = (ni * 2 + (c15 >> 3)) ^ ((q >> 1) & 3);
        Pw[q * 32 + sw * 8 + (c15 & 7)] = (unsigned short)(u >> 16);
      }

    // PV: read P as A-frag, V as B-frag (both swizzle-consistent)
    bf16x8 pf = *(const bf16x8*)(Pw + c15 * 32 + ((quad ^ ((c15 >> 1) & 3)) * 8));
#pragma unroll
    for (int nio = 0; nio < 4; nio++) {
      int R = nio * 16 + c15;
      bf16x8 vf = *(const bf16x8*)(Vb + R * 32 + ((quad ^ ((R >> 1) & 3)) * 8));
      of[nio] = __builtin_amdgcn_mfma_f32_16x16x32_bf16(pf, vf, of[nio], 0, 0, 0);
    }
    ol = __builtin_amdgcn_mfma_f32_16x16x32_bf16(pf, ones, ol, 0, 0, 0);

    __syncthreads();   // drains prefetch; guards buf reuse
  }

  // epilogue: direct write — each wave owns its 16 q rows end-to-end
#pragma unroll
  for (int r = 0; r < 4; r++) {
    float invl = 1.0f / ol[r];
    float* op = out + (size_t)(b * SS + q0 + quad * 4 + r) * DD + h * 64 + c15;
#pragma unroll
    for (int nio = 0; nio < 4; nio++)
      op[nio * 16] = of[nio][r] * invl;
  }
}

extern "C" void kernel_launch(void* const* d_in, const int* in_sizes, int n_in,
                              void* d_out, int out_size, void* d_ws, size_t ws_size,
                              hipStream_t stream) {
  (void)in_sizes; (void)n_in; (void)out_size; (void)ws_size;
  const float* X  = (const float*)d_in[0];
  const float* Wq = (const float*)d_in[1];
  const float* bq = (const float*)d_in[2];
  const float* Wk = (const float*)d_in[3];
  const float* bk = (const float*)d_in[4];
  const float* Wv = (const float*)d_in[5];
  const float* bv = (const float*)d_in[6];
  char* ws = (char*)d_ws;
  unsigned short* Xb  = (unsigned short*)(ws);                 // 4096x1280 bf16
  unsigned short* WT  = (unsigned short*)(ws + 10485760);      // 3x1280x1280 bf16 (transposed)
  unsigned short* Qr  = (unsigned short*)(ws + 20316160);      // 4096x1280 bf16 (rotary'd, scaled)
  unsigned short* Kr  = (unsigned short*)(ws + 30801920);      // 4096x1280 bf16 (rotary'd)
  unsigned short* VTt = (unsigned short*)(ws + 41287680);      // [40][64][2048] bf16
  float2* cstab       = (float2*)(ws + 51773440);              // 2048x32 float2
  hipLaunchKernelGGL(prep_kernel, dim3(7616), dim3(256), 0, stream, X, Wq, Wk, Wv, Xb, WT, cstab);
  hipLaunchKernelGGL(qkv_gemm_kernel, dim3(960), dim3(256), 0, stream, Xb, WT, bq, bk, bv, cstab, Qr, Kr, VTt);
  hipLaunchKernelGGL(attn_kernel, dim3(1280), dim3(256), 0, stream, Qr, Kr, VTt, (float*)d_out);
}

// Round 12
// 233.004 us; speedup vs baseline: 1.8786x; 1.0044x over previous
//
#include <hip/hip_runtime.h>

#define DD 1280
#define SS 2048
#define HH 20

typedef __bf16 bf16x8 __attribute__((ext_vector_type(8)));
typedef float f32x4 __attribute__((ext_vector_type(4)));

typedef __attribute__((address_space(3))) unsigned int lds_uint;
typedef __attribute__((address_space(1))) unsigned int glb_uint;
#define GLL16(g, l) __builtin_amdgcn_global_load_lds((const glb_uint*)(g), (lds_uint*)(l), 16, 0, 0)

__device__ __forceinline__ unsigned short f2bf(float f) {
  union { float f; unsigned u; } v; v.f = f;
  unsigned r = v.u + 0x7fffu + ((v.u >> 16) & 1u);
  return (unsigned short)(r >> 16);
}
__device__ __forceinline__ unsigned f2u(float f) {
  union { float f; unsigned u; } v; v.f = f; return v.u;
}
__device__ __forceinline__ unsigned pk2(float lo, float hi) {
  return ((unsigned)f2bf(hi) << 16) | (unsigned)f2bf(lo);
}

// ---- prep v3: few blocks, deep per-thread work (r11 postmortem: prep ~75us
// vs ~12us roofline; 7616 tiny blocks each one load->barrier->store round =
// dispatch/latency-bound, NOT instruction-count-bound -- r8's vectorization
// attacked the wrong axis).  v3: 1584 blocks, 4-8x work per thread:
//   X:  320 blocks x 8 iters (64 floats/thread, float4 loads, uint4 stores)
//   W:  64x64 tiles, 1200 blocks: 4x float4 -> LDS[64][68] -> 4x ushort4
//       transposed stores per thread (same verified v2 scatter/gather shape)
//   cs: 64 blocks x 4 iters
__global__ __launch_bounds__(256) void prep_kernel(
    const float* __restrict__ X, const float* __restrict__ Wq,
    const float* __restrict__ Wk, const float* __restrict__ Wv,
    unsigned short* __restrict__ Xb, unsigned short* __restrict__ WT,
    float2* __restrict__ cs) {
  __shared__ __align__(8) unsigned short tile[64][68];
  int bid = blockIdx.x, tid = threadIdx.x;
  if (bid < 320) {
#pragma unroll
    for (int it = 0; it < 8; it++) {
      size_t base = (size_t)(it * 320 + bid) * 2048 + (size_t)tid * 8;
      const float4* xin = (const float4*)(X + base);
      float4 a = xin[0], c = xin[1];
      uint4 o = make_uint4(pk2(a.x, a.y), pk2(a.z, a.w), pk2(c.x, c.y), pk2(c.z, c.w));
      *(uint4*)(Xb + base) = o;
    }
  } else if (bid < 1520) {
    int wb = bid - 320;           // 3 * 400 tiles of 64x64
    int mat = wb / 400;
    int t = wb % 400;
    int tn = t % 20, tk = t / 20;
    const float* W = (mat == 0) ? Wq : ((mat == 1) ? Wk : Wv);
    int k0 = tk * 64, n0 = tn * 64;
    int r = tid >> 2, cq = tid & 3;   // 256 threads = 64 rows x 4 col-chunks(16)
    const float* src = W + (size_t)(k0 + r) * DD + n0 + cq * 16;
#pragma unroll
    for (int j = 0; j < 4; j++) {
      float4 wv = *(const float4*)(src + j * 4);
      *(ushort4*)&tile[r][cq * 16 + j * 4] =
          make_ushort4(f2bf(wv.x), f2bf(wv.y), f2bf(wv.z), f2bf(wv.w));
    }
    __syncthreads();
    unsigned short* out = WT + (size_t)mat * DD * DD + (size_t)(n0 + r) * DD + k0 + cq * 16;
#pragma unroll
    for (int j = 0; j < 4; j++) {
      ushort4 o = make_ushort4(tile[cq * 16 + j * 4 + 0][r], tile[cq * 16 + j * 4 + 1][r],
                               tile[cq * 16 + j * 4 + 2][r], tile[cq * 16 + j * 4 + 3][r]);
      *(ushort4*)(out + j * 4) = o;
    }
  } else {
    // rotary table: cs[sp][j] = (cos, sin)(sp * 10000^(-j/32)), 2048 x 32
#pragma unroll
    for (int it = 0; it < 4; it++) {
      int idx = (bid - 1520) * 1024 + it * 256 + tid;   // 64 blocks -> 65536 entries
      int sp = idx >> 5, j = idx & 31;
      float invf = exp2f(-(float)j * 0.41524101186092034f);
      float ang = (float)sp * invf;
      cs[idx] = make_float2(cosf(ang), sinf(ang));
    }
  }
}

// ---- QKV GEMM: m97/BK=32 structure + T1 XCD-chunked swizzle (r8: proven) ----
__global__ __launch_bounds__(256) void qkv_gemm_kernel(
    const unsigned short* __restrict__ Xb, const unsigned short* __restrict__ WT,
    const float* __restrict__ bq, const float* __restrict__ bk, const float* __restrict__ bv,
    const float2* __restrict__ cs,
    unsigned short* __restrict__ Qr, unsigned short* __restrict__ Kr,
    unsigned short* __restrict__ VT) {
  __shared__ __align__(16) unsigned short As[128 * 32];
  __shared__ __align__(16) unsigned short Bs[128 * 32];
  int bx0 = blockIdx.x;           // 960 = 8 XCDs * 120
  int bx = (bx0 & 7) * 120 + (bx0 >> 3);   // XCD c works contiguous [c*120, c*120+120)
  int mat = bx / 320;
  int r0 = bx % 320;
  int tm = r0 / 10, tn = r0 % 10;
  int m0 = tm * 128, n0 = tn * 128;
  int tid = threadIdx.x;
  int lane = tid & 63, wave = tid >> 6;
  int c15 = lane & 15, quad = lane >> 4;
  int wm = wave >> 1, wn = wave & 1;
  const unsigned short* Wm = WT + (size_t)mat * DD * DD;

  int rowA = tid >> 2;
  int c8 = (tid & 3) * 8;
  const unsigned short* gA0 = Xb + (size_t)(m0 + rowA) * DD + c8;
  const unsigned short* gA1 = gA0 + (size_t)64 * DD;
  const unsigned short* gB0 = Wm + (size_t)(n0 + rowA) * DD + c8;
  const unsigned short* gB1 = gB0 + (size_t)64 * DD;
  unsigned short* ldsA0 = As + wave * 512;          // rows 0..63
  unsigned short* ldsA1 = As + 2048 + wave * 512;   // rows 64..127
  unsigned short* ldsB0 = Bs + wave * 512;
  unsigned short* ldsB1 = Bs + 2048 + wave * 512;

  f32x4 acc[4][4] = {};

  for (int kk = 0; kk < DD; kk += 32) {
    __syncthreads();
    GLL16(gA0 + kk, ldsA0);
    GLL16(gA1 + kk, ldsA1);
    GLL16(gB0 + kk, ldsB0);
    GLL16(gB1 + kk, ldsB1);
    __syncthreads();
    bf16x8 af[4];
#pragma unroll
    for (int mi = 0; mi < 4; mi++)
      af[mi] = *(const bf16x8*)(As + (wm * 64 + mi * 16 + c15) * 32 + quad * 8);
#pragma unroll
    for (int ni = 0; ni < 4; ni++) {
      bf16x8 bfr = *(const bf16x8*)(Bs + (wn * 64 + ni * 16 + c15) * 32 + quad * 8);
#pragma unroll
      for (int mi = 0; mi < 4; mi++)
        acc[mi][ni] = __builtin_amdgcn_mfma_f32_16x16x32_bf16(af[mi], bfr, acc[mi][ni], 0, 0, 0);
    }
  }

  int growb = m0 + wm * 64;
  int gcolb = n0 + wn * 64;
  if (mat == 2) {
    // V: write transposed VT[(b*H+h)*64+d][s]
#pragma unroll
    for (int mi = 0; mi < 4; mi++) {
      int row0 = growb + mi * 16 + quad * 4;
      int bb_ = row0 >> 11, sp = row0 & 2047;
#pragma unroll
      for (int ni = 0; ni < 4; ni++) {
        int gcol = gcolb + ni * 16 + c15;
        float bias = bv[gcol];
        int hh = gcol >> 6, dd = gcol & 63;
        f32x4 v = acc[mi][ni];
        ushort4 o = make_ushort4(f2bf(v[0] + bias), f2bf(v[1] + bias),
                                 f2bf(v[2] + bias), f2bf(v[3] + bias));
        *(ushort4*)(VT + ((size_t)((bb_ * HH + hh) * 64 + dd)) * SS + sp) = o;
      }
    }
  } else {
    // Q / K: bias + rotary via cs table
    unsigned short* Out = (mat == 0) ? Qr : Kr;
    const float* bias = (mat == 0) ? bq : bk;
    float qs = (mat == 0) ? 0.18033688011112042f : 1.0f;  // 0.125*log2(e) for Q
#pragma unroll
    for (int mi = 0; mi < 4; mi++) {
      int row0 = growb + mi * 16 + quad * 4;
#pragma unroll
      for (int ni = 0; ni < 2; ni++) {
        int gcol_lo = gcolb + ni * 16 + c15;      // d in [0,32) within head
        int gcol_hi = gcol_lo + 32;
        float blo = bias[gcol_lo], bhi = bias[gcol_hi];
        int d = ni * 16 + c15;
        f32x4 lo = acc[mi][ni], hi = acc[mi][ni + 2];
#pragma unroll
        for (int r = 0; r < 4; r++) {
          int grow = row0 + r;
          float2 cv = cs[(size_t)(grow & 2047) * 32 + d];
          float xl = (lo[r] + blo) * qs, xh = (hi[r] + bhi) * qs;
          Out[(size_t)grow * DD + gcol_lo] = f2bf(xl * cv.x - xh * cv.y);
          Out[(size_t)grow * DD + gcol_hi] = f2bf(xh * cv.x + xl * cv.y);
        }
      }
    }
  }
}

// ---- flash attention v14: q-split waves + LDS-shared K/V (r11: 89us, proven) ----
__global__ __launch_bounds__(256)
void attn_kernel(
    const unsigned short* __restrict__ Qr, const unsigned short* __restrict__ Kr,
    const unsigned short* __restrict__ VT, float* __restrict__ out) {
  __shared__ __align__(16) unsigned short Klds[2][2048];  // [buf][32k][64d]
  __shared__ __align__(16) unsigned short Vlds[2][2048];  // [buf][64d][32k]
  __shared__ __align__(16) unsigned short Pall[4][512];   // per-wave [16q][32k]
  int bx = blockIdx.x;             // bx = qt*40 + bh; head pinned to one XCD (40%8==0)
  int bh = bx % 40, qt = bx / 40;
  int b = bh / HH, h = bh % HH;
  int tid = threadIdx.x;
  int lane = tid & 63, w = tid >> 6;
  int c15 = lane & 15, quad = lane >> 4;
  int q0 = qt * 64 + w * 16;       // this wave's 16 q rows

  // Q fragments in registers (A-operand: m=c15, k=quad*8+j per 32-d chunk)
  const unsigned short* Qb = Qr + (size_t)(b * SS + q0 + c15) * DD + h * 64 + quad * 8;
  bf16x8 qf[2];
  qf[0] = *(const bf16x8*)(Qb);
  qf[1] = *(const bf16x8*)(Qb + 32);

  // staging sources (per-thread, inverse-swizzled global column)
  int krow = tid >> 3, kch = tid & 7;          // K: 32 rows x 8 chunks
  const unsigned short* Ksrc = Kr + (size_t)(b * SS + krow) * DD + h * 64
                               + ((kch ^ (krow & 7)) * 8);
  int vrow = tid >> 2, vch = tid & 3;          // V: 64 rows x 4 chunks
  const unsigned short* Vsrc = VT + (size_t)(bh * 64 + vrow) * SS
                               + ((vch ^ ((vrow >> 1) & 3)) * 8);
  unsigned short* Pw = &Pall[w][0];

  bf16x8 ones;
#pragma unroll
  for (int i = 0; i < 8; i++) ones[i] = (__bf16)1.0f;

  f32x4 of[4] = {};   // [nio]: O[q=quad*4+r][d=nio*16+c15]
  f32x4 ol = {};      // l[q=quad*4+r] via P*ones

  // prologue: stage tile 0 into buf 0
  GLL16(Ksrc, &Klds[0][0] + w * 512);
  GLL16(Vsrc, &Vlds[0][0] + w * 512);
  __syncthreads();

  for (int t = 0; t < 64; t++) {
    int buf = t & 1;
    if (t + 1 < 64) {   // prefetch next tile into the other buffer
      GLL16(Ksrc + (size_t)((t + 1) * 32) * DD, &Klds[buf ^ 1][0] + w * 512);
      GLL16(Vsrc + (t + 1) * 32, &Vlds[buf ^ 1][0] + w * 512);
    }
    const unsigned short* Kb = &Klds[buf][0];
    const unsigned short* Vb = &Vlds[buf][0];

    // QK^T: S[16q x 32k]
    f32x4 sc[2] = {};
#pragma unroll
    for (int kc = 0; kc < 2; kc++)
#pragma unroll
      for (int ni = 0; ni < 2; ni++) {
        int R = ni * 16 + c15;
        bf16x8 kf = *(const bf16x8*)(Kb + R * 64 + (((kc * 4 + quad) ^ (R & 7)) * 8));
        sc[ni] = __builtin_amdgcn_mfma_f32_16x16x32_bf16(qf[kc], kf, sc[ni], 0, 0, 0);
      }

    // exp2 + pack into this wave's P strip (swizzled)
#pragma unroll
    for (int ni = 0; ni < 2; ni++)
#pragma unroll
      for (int r = 0; r < 4; r++) {
        unsigned u = f2u(__builtin_amdgcn_exp2f(sc[ni][r]));
        int q = quad * 4 + r;
        int sw = (ni * 2 + (c15 >> 3)) ^ ((q >> 1) & 3);
        Pw[q * 32 + sw * 8 + (c15 & 7)] = (unsigned short)(u >> 16);
      }

    // PV: read P as A-frag, V as B-frag (both swizzle-consistent)
    bf16x8 pf = *(const bf16x8*)(Pw + c15 * 32 + ((quad ^ ((c15 >> 1) & 3)) * 8));
#pragma unroll
    for (int nio = 0; nio < 4; nio++) {
      int R = nio * 16 + c15;
      bf16x8 vf = *(const bf16x8*)(Vb + R * 32 + ((quad ^ ((R >> 1) & 3)) * 8));
      of[nio] = __builtin_amdgcn_mfma_f32_16x16x32_bf16(pf, vf, of[nio], 0, 0, 0);
    }
    ol = __builtin_amdgcn_mfma_f32_16x16x32_bf16(pf, ones, ol, 0, 0, 0);

    __syncthreads();   // drains prefetch; guards buf reuse
  }

  // epilogue: direct write — each wave owns its 16 q rows end-to-end
#pragma unroll
  for (int r = 0; r < 4; r++) {
    float invl = 1.0f / ol[r];
    float* op = out + (size_t)(b * SS + q0 + quad * 4 + r) * DD + h * 64 + c15;
#pragma unroll
    for (int nio = 0; nio < 4; nio++)
      op[nio * 16] = of[nio][r] * invl;
  }
}

extern "C" void kernel_launch(void* const* d_in, const int* in_sizes, int n_in,
                              void* d_out, int out_size, void* d_ws, size_t ws_size,
                              hipStream_t stream) {
  (void)in_sizes; (void)n_in; (void)out_size; (void)ws_size;
  const float* X  = (const float*)d_in[0];
  const float* Wq = (const float*)d_in[1];
  const float* bq = (const float*)d_in[2];
  const float* Wk = (const float*)d_in[3];
  const float* bk = (const float*)d_in[4];
  const float* Wv = (const float*)d_in[5];
  const float* bv = (const float*)d_in[6];
  char* ws = (char*)d_ws;
  unsigned short* Xb  = (unsigned short*)(ws);                 // 4096x1280 bf16
  unsigned short* WT  = (unsigned short*)(ws + 10485760);      // 3x1280x1280 bf16 (transposed)
  unsigned short* Qr  = (unsigned short*)(ws + 20316160);      // 4096x1280 bf16 (rotary'd, scaled)
  unsigned short* Kr  = (unsigned short*)(ws + 30801920);      // 4096x1280 bf16 (rotary'd)
  unsigned short* VTt = (unsigned short*)(ws + 41287680);      // [40][64][2048] bf16
  float2* cstab       = (float2*)(ws + 51773440);              // 2048x32 float2
  hipLaunchKernelGGL(prep_kernel, dim3(1584), dim3(256), 0, stream, X, Wq, Wk, Wv, Xb, WT, cstab);
  hipLaunchKernelGGL(qkv_gemm_kernel, dim3(960), dim3(256), 0, stream, Xb, WT, bq, bk, bv, cstab, Qr, Kr, VTt);
  hipLaunchKernelGGL(attn_kernel, dim3(1280), dim3(256), 0, stream, Qr, Kr, VTt, (float*)d_out);
}